// Round 4
// baseline (944.494 us; speedup 1.0000x reference)
//
#include <hip/hip_runtime.h>
#include <hip/hip_bf16.h>

typedef unsigned short u16;
typedef __attribute__((ext_vector_type(8))) short bf16x8;
typedef __attribute__((ext_vector_type(16))) float f32x16;

#define NROWS 4092      // 4 * 1023 valid token rows
#define NROWS_PAD 4096
#define DDIM 2048
#define VDIM 32768
#define NCHUNK 512      // 64-wide vocab chunks per row

// ---------- helpers ----------
__device__ __forceinline__ u16 f2bf(float f) {  // RNE fp32 -> bf16
  union { float f; unsigned u; } v; v.f = f;
  unsigned r = v.u + 0x7FFFu + ((v.u >> 16) & 1u);
  return (u16)(r >> 16);
}

__device__ __forceinline__ void gload16(const void* g, void* l) {
  using gp_t = const __attribute__((address_space(1))) unsigned*;
  using lp_t = __attribute__((address_space(3))) unsigned*;
  __builtin_amdgcn_global_load_lds((gp_t)g, (lp_t)(unsigned)(unsigned long long)l,
                                   16, 0, 0);
}

#define BAR() __builtin_amdgcn_s_barrier()
#define SB()  __builtin_amdgcn_sched_barrier(0)

// ---------- kernel 1: chosen ids (padded) + zero accumulators ----------
__global__ void init_k(const int* __restrict__ ids, int* __restrict__ chosen,
                       float* __restrict__ accum) {
  int i = blockIdx.x * 256 + threadIdx.x;
  if (i < NROWS_PAD) {
    int v = -1;
    if (i < NROWS) { int b = i / 1023, t = i % 1023; v = ids[b * 1024 + t + 1]; }
    chosen[i] = v;
  }
  if (i < 2) accum[i] = 0.f;
}

// ---------- kernel 2: h fp32 -> bf16, row-remapped, zero-padded ----------
__global__ void conv_h(const float* __restrict__ hs, u16* __restrict__ hb) {
  int idx = blockIdx.x * 256 + threadIdx.x;   // 2,097,152 threads
  int row = idx >> 9;
  int c4 = (idx & 511) << 2;
  ushort4 o;
  if (row < NROWS) {
    int b = row / 1023, t = row % 1023;
    float4 v = *(const float4*)(hs + (size_t)((b << 10) + t) * DDIM + c4);
    o = make_ushort4(f2bf(v.x), f2bf(v.y), f2bf(v.z), f2bf(v.w));
  } else {
    o = make_ushort4(0, 0, 0, 0);
  }
  *(ushort4*)(hb + (size_t)row * DDIM + c4) = o;
}

// ---------- kernel 3: W (D x V fp32) -> W^T (V x D bf16) ----------
__global__ void transpose_w(const float* __restrict__ W, u16* __restrict__ WT) {
  __shared__ u16 t[64 * 68];
  int v0 = blockIdx.x << 6, d0 = blockIdx.y << 6;
  int tid = threadIdx.x;
  int vi = (tid & 15) << 2, dl = tid >> 4;
#pragma unroll
  for (int i = 0; i < 4; ++i) {
    int d = dl + (i << 4);
    float4 w = *(const float4*)(W + (size_t)(d0 + d) * VDIM + v0 + vi);
    *(ushort4*)(&t[d * 68 + vi]) = make_ushort4(f2bf(w.x), f2bf(w.y), f2bf(w.z), f2bf(w.w));
  }
  __syncthreads();
  int d2 = (tid & 31) << 1, vb = tid >> 5;
#pragma unroll
  for (int i = 0; i < 8; ++i) {
    int v = vb + (i << 3);
    ushort2 o; o.x = t[d2 * 68 + v]; o.y = t[(d2 + 1) * 68 + v];
    *(ushort2*)(WT + (size_t)(v0 + v) * DDIM + d0 + d2) = o;
  }
}

// ---------- kernel 4: 256x256 GEMM, 32x32x16 MFMA, prefetch-under-MFMA ----
// A: [4096][2048] bf16 (zero-padded rows), Bt: [32768][2048] bf16
// LDS (dynamic 128 KiB): [buf][A/B][256 rows][128 B], XOR-swizzled reads with
// pre-permuted global sources (linear global_load_lds dest).
// Per tile: 4 sub-phases x 8 MFMA(32x32x16); each phase issues the NEXT
// phase's av reads then waits lgkmcnt(4) so the LDS pipe drains under MFMA.
// Barriers: mid-tile (B-space overwrite) + boundary (buffer flip); counted
// vmcnt(4) at boundary keeps B(t+2)'s 4 loads in flight (never drains).
__global__ __launch_bounds__(512, 2) void gemm_lse(
    const u16* __restrict__ A, const u16* __restrict__ Bt,
    const int* __restrict__ chosen,
    float2* __restrict__ partials, float* __restrict__ chlog) {
  extern __shared__ u16 smem[];
  char* lds = (char*)smem;

  const int tid = threadIdx.x;
  const int l = tid & 63;
  const int wid = tid >> 6;          // 8 waves
  const int wm = wid >> 2, wn = wid & 3;   // 2 x 4
  const int lo5 = l & 31, hi = l >> 5;

  // XCD-bijective swizzle (2048 blocks % 8 == 0)
  int bid = blockIdx.x;
  int id = ((bid & 7) << 8) | (bid >> 3);
  int bm = id & 15;                  // 0..15
  int bn = id >> 4;                  // 0..127
  const int m0 = bm << 8, n0 = bn << 8;

  const u16* Ab = A + (size_t)m0 * DDIM;
  const u16* Bb = Bt + (size_t)n0 * DDIM;

  // staging lane decomposition (linear LDS dest, pre-permuted global source)
  const int srow = l >> 3;
  const int sel = ((l & 7) ^ srow) << 3;

#define STAGE(bufB, abB, halfB, src, tt) do {                                  \
    char* _b = lds + (bufB) * 65536 + (abB) * 32768 + (halfB) * 16384;         \
    _Pragma("unroll")                                                          \
    for (int _j = 0; _j < 2; ++_j) {                                           \
      int _seg = (_j << 3) | wid;                                              \
      int _r = (_seg << 3) | srow;                                             \
      gload16((src) + (size_t)((halfB) * 128 + _r) * DDIM + ((tt) << 6) + sel, \
              _b + (_seg << 10));                                              \
    } } while (0)

  // 16-B unit index = (ks<<1)|hi, XOR'd with row&7 (conflict-free b128)
#define LDF(base, row, ks)                                                     \
  (*(const bf16x8*)(lds + (base) + (row) * 128 +                               \
                    (((((ks) << 1) | hi) ^ ((row) & 7)) << 4)))

#define MFMA_PH(mi, av) do {                                                   \
    __builtin_amdgcn_s_setprio(1);                                             \
    _Pragma("unroll")                                                          \
    for (int _ks = 0; _ks < 4; ++_ks)                                          \
      _Pragma("unroll")                                                        \
      for (int _ni = 0; _ni < 2; ++_ni)                                        \
        acc[mi][_ni] = __builtin_amdgcn_mfma_f32_32x32x16_bf16(                \
            (av)[_ks], bv[_ni][_ks], acc[mi][_ni], 0, 0, 0);                   \
    __builtin_amdgcn_s_setprio(0);                                             \
  } while (0)

#define WAITLG(n) do { asm volatile("s_waitcnt lgkmcnt(" #n ")" ::: "memory"); SB(); } while (0)

  f32x16 acc[4][2] = {};

  // prologue: tile0 full -> buf0; B(1) -> buf1.B; wait tile0, leave B(1) in flight
  STAGE(0, 0, 0, Ab, 0); STAGE(0, 0, 1, Ab, 0);
  STAGE(0, 1, 0, Bb, 0); STAGE(0, 1, 1, Bb, 0);
  STAGE(1, 1, 0, Bb, 1); STAGE(1, 1, 1, Bb, 1);
  asm volatile("s_waitcnt vmcnt(4)" ::: "memory"); SB();
  BAR();

  for (int t = 0; t < 32; ++t) {
    const int c = t & 1;
    const int abase = c << 16, bbase = (c << 16) + 32768;
    const int arow = (wm << 7) + lo5;
    const int brow = (wn << 6) + lo5;
    bf16x8 bv[2][4], avC[4], avN[4];

    // ---- q0: bv + av(mi0); prefetch av(mi1); stage A0(t+1)
#pragma unroll
    for (int ni = 0; ni < 2; ++ni)
#pragma unroll
      for (int ks = 0; ks < 4; ++ks)
        bv[ni][ks] = LDF(bbase, brow + (ni << 5), ks);
#pragma unroll
    for (int ks = 0; ks < 4; ++ks) avC[ks] = LDF(abase, arow, ks);
#pragma unroll
    for (int ks = 0; ks < 4; ++ks) avN[ks] = LDF(abase, arow + 32, ks);
    if (t < 31) STAGE(c ^ 1, 0, 0, Ab, t + 1);
    WAITLG(4);                       // bv + av(mi0) ready; av(mi1) in flight
    MFMA_PH(0, avC);
    // ---- q1: prefetch av(mi2); stage A1(t+1)
#pragma unroll
    for (int ks = 0; ks < 4; ++ks) avC[ks] = LDF(abase, arow + 64, ks);
    if (t < 31) STAGE(c ^ 1, 0, 1, Ab, t + 1);
    WAITLG(4);                       // av(mi1) ready
    MFMA_PH(1, avN);
    BAR();   // mid-tile: all waves' bv in regs -> B-space(c) writable
    // ---- q2: prefetch av(mi3); stage B0(t+2)
#pragma unroll
    for (int ks = 0; ks < 4; ++ks) avN[ks] = LDF(abase, arow + 96, ks);
    if (t < 30) STAGE(c, 1, 0, Bb, t + 2);
    WAITLG(4);                       // av(mi2) ready
    MFMA_PH(2, avC);
    // ---- q3: stage B1(t+2)
    if (t < 30) STAGE(c, 1, 1, Bb, t + 2);
    WAITLG(0);                       // av(mi3) ready
    MFMA_PH(3, avN);
    if (t < 30)       { asm volatile("s_waitcnt vmcnt(4)" ::: "memory"); }
    else if (t == 30) { asm volatile("s_waitcnt vmcnt(0)" ::: "memory"); }
    SB();
    BAR();   // boundary: tile t+1 fully landed, flip buffer
  }

  // epilogue: per-row (max, sum-exp) over this wave's 64 cols + chosen gather
  // 32x32 C/D layout: col = lane&31, row = (reg&3) + 8*(reg>>2) + 4*(lane>>5)
  const int chunk = (bn << 2) | wn;
  const int colb = n0 + (wn << 6) + lo5;
#pragma unroll
  for (int mi = 0; mi < 4; ++mi) {
#pragma unroll
    for (int rg = 0; rg < 16; ++rg) {
      const int row = m0 + (wm << 7) + (mi << 5) +
                      (rg & 3) + ((rg >> 2) << 3) + (hi << 2);
      float v0 = acc[mi][0][rg], v1 = acc[mi][1][rg];
      float mx = fmaxf(v0, v1);
#pragma unroll
      for (int o = 1; o < 32; o <<= 1) mx = fmaxf(mx, __shfl_xor(mx, o, 64));
      float s = __expf(v0 - mx) + __expf(v1 - mx);
#pragma unroll
      for (int o = 1; o < 32; o <<= 1) s += __shfl_xor(s, o, 64);
      if (lo5 == 0) partials[(size_t)row * NCHUNK + chunk] = make_float2(mx, s);
      const int cc = chosen[row];   // -1 on pad rows -> never matches
      if (cc == colb)      chlog[row] = v0;
      if (cc == colb + 32) chlog[row] = v1;
    }
  }
#undef STAGE
#undef LDF
#undef MFMA_PH
#undef WAITLG
}

// ---------- kernel 5: combine partials -> lse -> logps -> loss terms ----------
__global__ void reduce_lse(const float2* __restrict__ partials,
                           const float* __restrict__ chlog,
                           const float* __restrict__ oldlp,
                           const int* __restrict__ labels,
                           const float* __restrict__ adv,
                           float* __restrict__ out, float* __restrict__ accum) {
  const int wid = threadIdx.x >> 6, l = threadIdx.x & 63;
  const int row = blockIdx.x * 4 + wid;        // 1023*4 = 4092 exactly
  float M = -INFINITY, S = 0.f;
  for (int c = l; c < NCHUNK; c += 64) {
    float2 p = partials[(size_t)row * NCHUNK + c];
    float Mn = fmaxf(M, p.x);
    S = S * __expf(M - Mn) + p.y * __expf(p.x - Mn);
    M = Mn;
  }
#pragma unroll
  for (int o = 1; o < 64; o <<= 1) {
    float Mo = __shfl_xor(M, o, 64), So = __shfl_xor(S, o, 64);
    float Mn = fmaxf(M, Mo);
    S = S * __expf(M - Mn) + So * __expf(Mo - Mn);
    M = Mn;
  }
  if (l == 0) {
    float lse = M + __logf(S);
    float ptl = chlog[row] - lse;
    out[1 + row] = ptl;
    int b = row / 1023, t = row % 1023;
    float a = adv[b];
    float ratio = __expf(ptl - oldlp[row]);
    float l1 = ratio * a;
    float l2 = fminf(fmaxf(ratio, 0.8f), 1.3f) * a;
    float mk = (float)labels[b * 1024 + t + 1];
    atomicAdd(accum + 0, -fminf(l1, l2) * mk);
    atomicAdd(accum + 1, mk);
  }
}

__global__ void finalize_k(const float* __restrict__ accum, float* __restrict__ out) {
  out[0] = accum[0] / accum[1];
}

// ---------- launch ----------
extern "C" void kernel_launch(void* const* d_in, const int* in_sizes, int n_in,
                              void* d_out, int out_size, void* d_ws, size_t ws_size,
                              hipStream_t stream) {
  const float* hs     = (const float*)d_in[0];   // (4,1024,2048)
  const float* W      = (const float*)d_in[1];   // (2048,32768)
  const int*   ids    = (const int*)d_in[2];     // (4,1024)
  const int*   labels = (const int*)d_in[3];     // (4,1024)
  const float* adv    = (const float*)d_in[4];   // (4,)
  const float* oldlp  = (const float*)d_in[5];   // (4,1023)
  float* out = (float*)d_out;                    // [loss, 4092 x per_token_logps]

  char* ws = (char*)d_ws;
  u16*    WT       = (u16*)ws;                         // 134,217,728 B
  u16*    hb       = (u16*)(ws + 134217728);           //  16,777,216 B
  float2* partials = (float2*)(ws + 150994944);        //  16,777,216 B
  float*  chlog    = (float*)(ws + 167772160);         //      16,384 B
  int*    chosen   = (int*)(ws + 167788544);           //      16,384 B
  float*  accum    = (float*)(ws + 167804928);         //           8 B

  (void)hipFuncSetAttribute((const void*)gemm_lse,
                            hipFuncAttributeMaxDynamicSharedMemorySize, 131072);

  init_k<<<16, 256, 0, stream>>>(ids, chosen, accum);
  conv_h<<<8192, 256, 0, stream>>>(hs, hb);
  transpose_w<<<dim3(512, 32), 256, 0, stream>>>(W, WT);
  gemm_lse<<<2048, 512, 131072, stream>>>(hb, WT, chosen, partials, chlog);
  reduce_lse<<<1023, 256, 0, stream>>>(partials, chlog, oldlp, labels, adv, out, accum);
  finalize_k<<<1, 1, 0, stream>>>(accum, out);
}

// Round 5
// 743.863 us; speedup vs baseline: 1.2697x; 1.2697x over previous
//
#include <hip/hip_runtime.h>
#include <hip/hip_bf16.h>

typedef unsigned short u16;
typedef __attribute__((ext_vector_type(8))) short bf16x8;
typedef __attribute__((ext_vector_type(4))) float f32x4;

#define NROWS 4092      // 4 * 1023 valid token rows
#define NROWS_PAD 4096
#define DDIM 2048
#define VDIM 32768
#define NCHUNK 512      // 64-wide vocab chunks per row

// ---------- helpers ----------
__device__ __forceinline__ u16 f2bf(float f) {  // RNE fp32 -> bf16
  union { float f; unsigned u; } v; v.f = f;
  unsigned r = v.u + 0x7FFFu + ((v.u >> 16) & 1u);
  return (u16)(r >> 16);
}

__device__ __forceinline__ void gload16(const void* g, void* l) {
  using gp_t = const __attribute__((address_space(1))) unsigned*;
  using lp_t = __attribute__((address_space(3))) unsigned*;
  __builtin_amdgcn_global_load_lds((gp_t)g, (lp_t)(unsigned)(unsigned long long)l,
                                   16, 0, 0);
}

#define BAR() __builtin_amdgcn_s_barrier()
#define SB()  __builtin_amdgcn_sched_barrier(0)

// ---------- kernel 1: chosen ids (padded) + zero accumulators ----------
__global__ void init_k(const int* __restrict__ ids, int* __restrict__ chosen,
                       float* __restrict__ accum) {
  int i = blockIdx.x * 256 + threadIdx.x;
  if (i < NROWS_PAD) {
    int v = -1;
    if (i < NROWS) { int b = i / 1023, t = i % 1023; v = ids[b * 1024 + t + 1]; }
    chosen[i] = v;
  }
  if (i < 2) accum[i] = 0.f;
}

// ---------- kernel 2: h fp32 -> bf16, row-remapped, zero-padded ----------
__global__ void conv_h(const float* __restrict__ hs, u16* __restrict__ hb) {
  int idx = blockIdx.x * 256 + threadIdx.x;   // 2,097,152 threads
  int row = idx >> 9;
  int c4 = (idx & 511) << 2;
  ushort4 o;
  if (row < NROWS) {
    int b = row / 1023, t = row % 1023;
    float4 v = *(const float4*)(hs + (size_t)((b << 10) + t) * DDIM + c4);
    o = make_ushort4(f2bf(v.x), f2bf(v.y), f2bf(v.z), f2bf(v.w));
  } else {
    o = make_ushort4(0, 0, 0, 0);
  }
  *(ushort4*)(hb + (size_t)row * DDIM + c4) = o;
}

// ---------- kernel 3: W (D x V fp32) -> W^T (V x D bf16) ----------
__global__ void transpose_w(const float* __restrict__ W, u16* __restrict__ WT) {
  __shared__ u16 t[64 * 68];
  int v0 = blockIdx.x << 6, d0 = blockIdx.y << 6;
  int tid = threadIdx.x;
  int vi = (tid & 15) << 2, dl = tid >> 4;
#pragma unroll
  for (int i = 0; i < 4; ++i) {
    int d = dl + (i << 4);
    float4 w = *(const float4*)(W + (size_t)(d0 + d) * VDIM + v0 + vi);
    *(ushort4*)(&t[d * 68 + vi]) = make_ushort4(f2bf(w.x), f2bf(w.y), f2bf(w.z), f2bf(w.w));
  }
  __syncthreads();
  int d2 = (tid & 31) << 1, vb = tid >> 5;
#pragma unroll
  for (int i = 0; i < 8; ++i) {
    int v = vb + (i << 3);
    ushort2 o; o.x = t[d2 * 68 + v]; o.y = t[(d2 + 1) * 68 + v];
    *(ushort2*)(WT + (size_t)(v0 + v) * DDIM + d0 + d2) = o;
  }
}

// ---------- kernel 4: 256x256 GEMM, m201-style per-phase barrier pacing ----
// A: [4096][2048] bf16 (zero-padded rows), Bt: [32768][2048] bf16
// LDS (dynamic 128 KiB): [buf][A/B][half(128 rows)][128 B/row], XOR-swizzled
// reads, pre-permuted global sources (linear global_load_lds dest).
// Per tile (BK=64): 4 phases, each = {reads; stage half-tile; BAR;
// lgkmcnt(0); setprio(1); 16 MFMA; setprio(0); BAR}. Counted vmcnt(4) at
// phase 3 only (B(t+2)'s 4 loads stay in flight across the flip).
__global__ __launch_bounds__(512, 2) void gemm_lse(
    const u16* __restrict__ A, const u16* __restrict__ Bt,
    const int* __restrict__ chosen,
    float2* __restrict__ partials, float* __restrict__ chlog) {
  extern __shared__ u16 smem[];
  char* lds = (char*)smem;

  const int tid = threadIdx.x;
  const int l = tid & 63;
  const int wid = tid >> 6;          // 8 waves
  const int wm = wid >> 2, wn = wid & 3;   // 2 x 4
  const int ln = l & 15;
  const int g4 = l >> 4;

  // XCD-bijective swizzle (2048 blocks % 8 == 0)
  int bid = blockIdx.x;
  int id = ((bid & 7) << 8) | (bid >> 3);
  int bm = id & 15;                  // 0..15
  int bn = id >> 4;                  // 0..127
  const int m0 = bm << 8, n0 = bn << 8;

  const u16* Ab = A + (size_t)m0 * DDIM;
  const u16* Bb = Bt + (size_t)n0 * DDIM;

  // staging lane decomposition (linear LDS dest, pre-permuted global source)
  const int srow = l >> 3;
  const int sel = ((l & 7) ^ srow) << 3;

#define STAGE(bufB, abB, halfB, src, tt) do {                                  \
    char* _b = lds + (bufB) * 65536 + (abB) * 32768 + (halfB) * 16384;         \
    _Pragma("unroll")                                                          \
    for (int _j = 0; _j < 2; ++_j) {                                           \
      int _seg = (_j << 3) | wid;                                              \
      int _r = (_seg << 3) | srow;                                             \
      gload16((src) + (size_t)((halfB) * 128 + _r) * DDIM + ((tt) << 6) + sel, \
              _b + (_seg << 10));                                              \
    } } while (0)

#define LDA(buf, arow, h)                                                      \
  (*(const bf16x8*)(lds + (buf) * 65536 + ((arow) >> 7) * 16384 +              \
                    ((arow) & 127) * 128 +                                     \
                    (((((h) << 2) | g4) ^ ((arow) & 7)) << 4)))
#define LDB(buf, brow, h)                                                      \
  (*(const bf16x8*)(lds + (buf) * 65536 + 32768 + ((brow) >> 7) * 16384 +      \
                    ((brow) & 127) * 128 +                                     \
                    (((((h) << 2) | g4) ^ ((brow) & 7)) << 4)))

#define LOADAV(q) do {                                                         \
    _Pragma("unroll")                                                          \
    for (int _i = 0; _i < 2; ++_i)                                             \
      _Pragma("unroll")                                                        \
      for (int _h = 0; _h < 2; ++_h)                                           \
        av[_i][_h] = LDA(c, (wm << 7) + (((((q) << 1)) + _i) << 4) + ln, _h);  \
  } while (0)

#define MFMA_Q(q) do {                                                         \
    __builtin_amdgcn_s_setprio(1);                                             \
    _Pragma("unroll")                                                          \
    for (int _h = 0; _h < 2; ++_h)                                             \
      _Pragma("unroll")                                                        \
      for (int _i = 0; _i < 2; ++_i)                                           \
        _Pragma("unroll")                                                      \
        for (int _ni = 0; _ni < 4; ++_ni)                                      \
          acc[((q) << 1) + _i][_ni] = __builtin_amdgcn_mfma_f32_16x16x32_bf16( \
              av[_i][_h], bv[_ni][_h], acc[((q) << 1) + _i][_ni], 0, 0, 0);    \
    __builtin_amdgcn_s_setprio(0);                                             \
  } while (0)

#define WAITLG0() do { asm volatile("s_waitcnt lgkmcnt(0)" ::: "memory"); SB(); } while (0)

  f32x4 acc[8][4] = {};

  // prologue: tile0 full -> buf0; B(1) -> buf1.B; wait tile0, leave B(1) in flight
  STAGE(0, 0, 0, Ab, 0); STAGE(0, 0, 1, Ab, 0);
  STAGE(0, 1, 0, Bb, 0); STAGE(0, 1, 1, Bb, 0);
  STAGE(1, 1, 0, Bb, 1); STAGE(1, 1, 1, Bb, 1);
  asm volatile("s_waitcnt vmcnt(4)" ::: "memory"); SB();
  BAR();

  for (int t = 0; t < 32; ++t) {
    const int c = t & 1;
    bf16x8 bv[4][2], av[2][2];

    // ---- phase 0: bv(8) + av q0(4); stage A0(t+1)
#pragma unroll
    for (int ni = 0; ni < 4; ++ni)
#pragma unroll
      for (int h = 0; h < 2; ++h)
        bv[ni][h] = LDB(c, (wn << 6) + (ni << 4) + ln, h);
    LOADAV(0);
    if (t < 31) STAGE(c ^ 1, 0, 0, Ab, t + 1);
    asm volatile("s_waitcnt lgkmcnt(8)" ::: "memory"); SB();  // pace the 12-read burst
    BAR();
    WAITLG0();
    MFMA_Q(0);
    BAR();
    // ---- phase 1: av q1(4); stage A1(t+1)
    LOADAV(1);
    if (t < 31) STAGE(c ^ 1, 0, 1, Ab, t + 1);
    BAR();
    WAITLG0();
    MFMA_Q(1);
    BAR();
    // ---- phase 2: av q2(4); stage B0(t+2) into current buf's B-space
    //  (safe: all waves' bv completed before their phase-0 MFMA barrier)
    LOADAV(2);
    if (t < 30) STAGE(c, 1, 0, Bb, t + 2);
    BAR();
    WAITLG0();
    MFMA_Q(2);
    BAR();
    // ---- phase 3: av q3(4); stage B1(t+2); counted vmcnt; flip
    LOADAV(3);
    if (t < 30) STAGE(c, 1, 1, Bb, t + 2);
    if (t < 30)       { asm volatile("s_waitcnt vmcnt(4)" ::: "memory"); }
    else if (t == 30) { asm volatile("s_waitcnt vmcnt(0)" ::: "memory"); }
    SB();
    BAR();
    WAITLG0();
    MFMA_Q(3);
    BAR();
  }

  // epilogue: per-row (max, sum-exp) over this wave's 64 cols + chosen gather
  // C/D layout: col = lane&15, row = (lane>>4)*4 + reg
  const int chunk = (bn << 2) | wn;
  const int colb = n0 + (wn << 6) + ln;
#pragma unroll
  for (int mi = 0; mi < 8; ++mi) {
#pragma unroll
    for (int rr = 0; rr < 4; ++rr) {
      const int row = m0 + (wm << 7) + (mi << 4) + (g4 << 2) + rr;
      float v0 = acc[mi][0][rr], v1 = acc[mi][1][rr];
      float v2 = acc[mi][2][rr], v3 = acc[mi][3][rr];
      float mx = fmaxf(fmaxf(v0, v1), fmaxf(v2, v3));
#pragma unroll
      for (int o = 1; o < 16; o <<= 1) mx = fmaxf(mx, __shfl_xor(mx, o, 64));
      float s = __expf(v0 - mx) + __expf(v1 - mx) + __expf(v2 - mx) + __expf(v3 - mx);
#pragma unroll
      for (int o = 1; o < 16; o <<= 1) s += __shfl_xor(s, o, 64);
      if (ln == 0) partials[(size_t)row * NCHUNK + chunk] = make_float2(mx, s);
      const int cc = chosen[row];   // -1 on pad rows -> never matches
      if (cc == colb)      chlog[row] = v0;
      if (cc == colb + 16) chlog[row] = v1;
      if (cc == colb + 32) chlog[row] = v2;
      if (cc == colb + 48) chlog[row] = v3;
    }
  }
#undef STAGE
#undef LDA
#undef LDB
#undef LOADAV
#undef MFMA_Q
#undef WAITLG0
}

// ---------- kernel 5: combine partials -> lse -> logps -> loss terms ----------
__global__ void reduce_lse(const float2* __restrict__ partials,
                           const float* __restrict__ chlog,
                           const float* __restrict__ oldlp,
                           const int* __restrict__ labels,
                           const float* __restrict__ adv,
                           float* __restrict__ out, float* __restrict__ accum) {
  const int wid = threadIdx.x >> 6, l = threadIdx.x & 63;
  const int row = blockIdx.x * 4 + wid;        // 1023*4 = 4092 exactly
  float M = -INFINITY, S = 0.f;
  for (int c = l; c < NCHUNK; c += 64) {
    float2 p = partials[(size_t)row * NCHUNK + c];
    float Mn = fmaxf(M, p.x);
    S = S * __expf(M - Mn) + p.y * __expf(p.x - Mn);
    M = Mn;
  }
#pragma unroll
  for (int o = 1; o < 64; o <<= 1) {
    float Mo = __shfl_xor(M, o, 64), So = __shfl_xor(S, o, 64);
    float Mn = fmaxf(M, Mo);
    S = S * __expf(M - Mn) + So * __expf(Mo - Mn);
    M = Mn;
  }
  if (l == 0) {
    float lse = M + __logf(S);
    float ptl = chlog[row] - lse;
    out[1 + row] = ptl;
    int b = row / 1023, t = row % 1023;
    float a = adv[b];
    float ratio = __expf(ptl - oldlp[row]);
    float l1 = ratio * a;
    float l2 = fminf(fmaxf(ratio, 0.8f), 1.3f) * a;
    float mk = (float)labels[b * 1024 + t + 1];
    atomicAdd(accum + 0, -fminf(l1, l2) * mk);
    atomicAdd(accum + 1, mk);
  }
}

__global__ void finalize_k(const float* __restrict__ accum, float* __restrict__ out) {
  out[0] = accum[0] / accum[1];
}

// ---------- launch ----------
extern "C" void kernel_launch(void* const* d_in, const int* in_sizes, int n_in,
                              void* d_out, int out_size, void* d_ws, size_t ws_size,
                              hipStream_t stream) {
  const float* hs     = (const float*)d_in[0];   // (4,1024,2048)
  const float* W      = (const float*)d_in[1];   // (2048,32768)
  const int*   ids    = (const int*)d_in[2];     // (4,1024)
  const int*   labels = (const int*)d_in[3];     // (4,1024)
  const float* adv    = (const float*)d_in[4];   // (4,)
  const float* oldlp  = (const float*)d_in[5];   // (4,1023)
  float* out = (float*)d_out;                    // [loss, 4092 x per_token_logps]

  char* ws = (char*)d_ws;
  u16*    WT       = (u16*)ws;                         // 134,217,728 B
  u16*    hb       = (u16*)(ws + 134217728);           //  16,777,216 B
  float2* partials = (float2*)(ws + 150994944);        //  16,777,216 B
  float*  chlog    = (float*)(ws + 167772160);         //      16,384 B
  int*    chosen   = (int*)(ws + 167788544);           //      16,384 B
  float*  accum    = (float*)(ws + 167804928);         //           8 B

  (void)hipFuncSetAttribute((const void*)gemm_lse,
                            hipFuncAttributeMaxDynamicSharedMemorySize, 131072);

  init_k<<<16, 256, 0, stream>>>(ids, chosen, accum);
  conv_h<<<8192, 256, 0, stream>>>(hs, hb);
  transpose_w<<<dim3(512, 32), 256, 0, stream>>>(W, WT);
  gemm_lse<<<2048, 512, 131072, stream>>>(hb, WT, chosen, partials, chlog);
  reduce_lse<<<1023, 256, 0, stream>>>(partials, chlog, oldlp, labels, adv, out, accum);
  finalize_k<<<1, 1, 0, stream>>>(accum, out);
}

// Round 6
// 718.856 us; speedup vs baseline: 1.3139x; 1.0348x over previous
//
#include <hip/hip_runtime.h>
#include <hip/hip_bf16.h>

typedef unsigned short u16;
typedef __attribute__((ext_vector_type(8))) short bf16x8;
typedef __attribute__((ext_vector_type(4))) float f32x4;

#define NROWS 4092      // 4 * 1023 valid token rows
#define NROWS_PAD 4096
#define DDIM 2048
#define VDIM 32768
#define NCHUNK 512      // 64-wide vocab chunks per row

// ---------- helpers ----------
__device__ __forceinline__ u16 f2bf(float f) {  // RNE fp32 -> bf16
  union { float f; unsigned u; } v; v.f = f;
  unsigned r = v.u + 0x7FFFu + ((v.u >> 16) & 1u);
  return (u16)(r >> 16);
}

__device__ __forceinline__ void gload16(const void* g, void* l) {
  using gp_t = const __attribute__((address_space(1))) unsigned*;
  using lp_t = __attribute__((address_space(3))) unsigned*;
  __builtin_amdgcn_global_load_lds((gp_t)g, (lp_t)(unsigned)(unsigned long long)l,
                                   16, 0, 0);
}

#define BAR() __builtin_amdgcn_s_barrier()
#define SB()  __builtin_amdgcn_sched_barrier(0)
// inline-asm ds_read_b128 with literal offset; earlyclobber output
#define DSR(d, a, o) asm volatile("ds_read_b128 %0, %1 offset:" o : "=&v"(d) : "v"(a))
#define WAITLG(n) do { asm volatile("s_waitcnt lgkmcnt(" #n ")" ::: "memory"); SB(); } while (0)

// ---------- kernel 1: chosen ids (padded) + zero accumulators ----------
__global__ void init_k(const int* __restrict__ ids, int* __restrict__ chosen,
                       float* __restrict__ accum) {
  int i = blockIdx.x * 256 + threadIdx.x;
  if (i < NROWS_PAD) {
    int v = -1;
    if (i < NROWS) { int b = i / 1023, t = i % 1023; v = ids[b * 1024 + t + 1]; }
    chosen[i] = v;
  }
  if (i < 2) accum[i] = 0.f;
}

// ---------- kernel 2: h fp32 -> bf16, row-remapped, zero-padded ----------
__global__ void conv_h(const float* __restrict__ hs, u16* __restrict__ hb) {
  int idx = blockIdx.x * 256 + threadIdx.x;   // 2,097,152 threads
  int row = idx >> 9;
  int c4 = (idx & 511) << 2;
  ushort4 o;
  if (row < NROWS) {
    int b = row / 1023, t = row % 1023;
    float4 v = *(const float4*)(hs + (size_t)((b << 10) + t) * DDIM + c4);
    o = make_ushort4(f2bf(v.x), f2bf(v.y), f2bf(v.z), f2bf(v.w));
  } else {
    o = make_ushort4(0, 0, 0, 0);
  }
  *(ushort4*)(hb + (size_t)row * DDIM + c4) = o;
}

// ---------- kernel 3: W (D x V fp32) -> W^T (V x D bf16) ----------
__global__ void transpose_w(const float* __restrict__ W, u16* __restrict__ WT) {
  __shared__ u16 t[64 * 68];
  int v0 = blockIdx.x << 6, d0 = blockIdx.y << 6;
  int tid = threadIdx.x;
  int vi = (tid & 15) << 2, dl = tid >> 4;
#pragma unroll
  for (int i = 0; i < 4; ++i) {
    int d = dl + (i << 4);
    float4 w = *(const float4*)(W + (size_t)(d0 + d) * VDIM + v0 + vi);
    *(ushort4*)(&t[d * 68 + vi]) = make_ushort4(f2bf(w.x), f2bf(w.y), f2bf(w.z), f2bf(w.w));
  }
  __syncthreads();
  // write: 16 threads cover one v-row (64 d as ushort4) -> 128B coalesced
  int dv = (tid & 15) << 2, vr = tid >> 4;
#pragma unroll
  for (int i = 0; i < 4; ++i) {
    int v = vr + (i << 4);
    ushort4 o;
    o.x = t[(dv + 0) * 68 + v]; o.y = t[(dv + 1) * 68 + v];
    o.z = t[(dv + 2) * 68 + v]; o.w = t[(dv + 3) * 68 + v];
    *(ushort4*)(WT + (size_t)(v0 + v) * DDIM + d0 + dv) = o;
  }
}

// ---------- kernel 4: 256x256 GEMM, strength-reduced addressing ----------
// A: [4096][2048] bf16 (zero-padded rows), Bt: [32768][2048] bf16
// LDS (dynamic 128 KiB): [buf][A/B][half(128 rows)][128 B/row], XOR-swizzled
// reads with pre-permuted global sources (linear global_load_lds dest).
// All LDS read addrs precomputed (4 bases + offset: immediates); buffer flip
// is one XOR per addr per tile; stage pointers advance +128B/tile.
// Schedule (R3 skeleton): reads one phase ahead w/ counted lgkmcnt(4);
// 2 barriers/tile; counted vmcnt(4) at boundary (B(t+2) stays in flight).
__global__ __launch_bounds__(512, 2) void gemm_lse(
    const u16* __restrict__ A, const u16* __restrict__ Bt,
    const int* __restrict__ chosen,
    float2* __restrict__ partials, float* __restrict__ chlog) {
  extern __shared__ u16 smem[];
  char* lds = (char*)smem;
  const unsigned lbase = (unsigned)(unsigned long long)lds;

  const int tid = threadIdx.x;
  const int l = tid & 63;
  const int wid = tid >> 6;          // 8 waves
  const int wm = wid >> 2, wn = wid & 3;   // 2 x 4
  const int ln = l & 15;
  const int g4 = l >> 4;
  const int xr = ln & 7;

  // XCD-bijective swizzle (2048 blocks % 8 == 0)
  int bid = blockIdx.x;
  int id = ((bid & 7) << 8) | (bid >> 3);
  int bm = id & 15;                  // 0..15
  int bn = id >> 4;                  // 0..127
  const int m0 = bm << 8, n0 = bn << 8;

  const u16* Ab = A + (size_t)m0 * DDIM;
  const u16* Bb = Bt + (size_t)n0 * DDIM;

  // ---- precomputed swizzled LDS READ addresses (c=0; flip ^0x10000/tile) ---
  // A: addr = wm*16384 + ln*128 + ((h*4+g4)^xr)*16   (+ mi*2048 as imm)
  // B: addr = 32768 + (wn>>1)*16384 + ((wn&1)*64+ln)*128 + ((h*4+g4)^xr)*16
  unsigned aR0 = lbase + (wm << 14) + (ln << 7) + (((0 | g4) ^ xr) << 4);
  unsigned aR1 = lbase + (wm << 14) + (ln << 7) + (((4 | g4) ^ xr) << 4);
  unsigned bR0 = lbase + 32768 + ((wn >> 1) << 14) + (((((wn & 1) << 6) | ln)) << 7) + (((0 | g4) ^ xr) << 4);
  unsigned bR1 = lbase + 32768 + ((wn >> 1) << 14) + (((((wn & 1) << 6) | ln)) << 7) + (((4 | g4) ^ xr) << 4);

  // ---- stage LDS dests (init: A->buf1, B->buf0; flip ^0x10000/tile) ----
  unsigned dA00 = 65536 + (wid << 10),         dA01 = 65536 + ((8 + wid) << 10);
  unsigned dA10 = 65536 + 16384 + (wid << 10), dA11 = 65536 + 16384 + ((8 + wid) << 10);
  unsigned dB00 = 32768 + (wid << 10),         dB01 = 32768 + ((8 + wid) << 10);
  unsigned dB10 = 49152 + (wid << 10),         dB11 = 49152 + ((8 + wid) << 10);

  // ---- stage global pointers (pre-permuted source; advance +64 elem/tile) --
  const int srow = l >> 3;
  const int sel = ((l & 7) ^ srow) << 3;
  const int r0 = (wid << 3) | srow;          // rows 0..63
  const int r1 = ((8 + wid) << 3) | srow;    // rows 64..127
  const u16* pA00 = Ab + (size_t)r0 * DDIM + sel + 64;          // A(1) half0
  const u16* pA01 = Ab + (size_t)r1 * DDIM + sel + 64;
  const u16* pA10 = Ab + (size_t)(128 + r0) * DDIM + sel + 64;  // A(1) half1
  const u16* pA11 = Ab + (size_t)(128 + r1) * DDIM + sel + 64;
  const u16* pB00 = Bb + (size_t)r0 * DDIM + sel + 128;         // B(2) half0
  const u16* pB01 = Bb + (size_t)r1 * DDIM + sel + 128;
  const u16* pB10 = Bb + (size_t)(128 + r0) * DDIM + sel + 128; // B(2) half1
  const u16* pB11 = Bb + (size_t)(128 + r1) * DDIM + sel + 128;

#define MFMA_Q(q, av) do {                                                     \
    __builtin_amdgcn_s_setprio(1);                                             \
    _Pragma("unroll")                                                          \
    for (int _h = 0; _h < 2; ++_h)                                             \
      _Pragma("unroll")                                                        \
      for (int _i = 0; _i < 2; ++_i)                                           \
        _Pragma("unroll")                                                      \
        for (int _ni = 0; _ni < 4; ++_ni)                                      \
          acc[((q) << 1) + _i][_ni] = __builtin_amdgcn_mfma_f32_16x16x32_bf16( \
              (av)[_i][_h], bv[_ni][_h], acc[((q) << 1) + _i][_ni], 0, 0, 0);  \
    __builtin_amdgcn_s_setprio(0);                                             \
  } while (0)

#define LOADAV(dst, O0, O1) do {                                               \
    DSR(dst[0][0], aR0, O0); DSR(dst[0][1], aR1, O0);                          \
    DSR(dst[1][0], aR0, O1); DSR(dst[1][1], aR1, O1); } while (0)

  f32x4 acc[8][4] = {};

  // prologue: A(0),B(0) -> buf0; B(1) -> buf1; wait both tile0 halves landed
  gload16(pA00 - 64, lds + (dA00 ^ 65536)); gload16(pA01 - 64, lds + (dA01 ^ 65536));
  gload16(pA10 - 64, lds + (dA10 ^ 65536)); gload16(pA11 - 64, lds + (dA11 ^ 65536));
  gload16(pB00 - 128, lds + dB00); gload16(pB01 - 128, lds + dB01);
  gload16(pB10 - 128, lds + dB10); gload16(pB11 - 128, lds + dB11);
  gload16(pB00 - 64, lds + (dB00 ^ 65536)); gload16(pB01 - 64, lds + (dB01 ^ 65536));
  gload16(pB10 - 64, lds + (dB10 ^ 65536)); gload16(pB11 - 64, lds + (dB11 ^ 65536));
  asm volatile("s_waitcnt vmcnt(4)" ::: "memory"); SB();
  BAR();

  for (int t = 0; t < 32; ++t) {
    bf16x8 bv[4][2], avA[2][2], avB[2][2];
    // ---- q0: bv(8) + avA q0(4); stage A0(t+1); prefetch avB q1(4)
    DSR(bv[0][0], bR0, "0");    DSR(bv[1][0], bR0, "2048");
    DSR(bv[2][0], bR0, "4096"); DSR(bv[3][0], bR0, "6144");
    DSR(bv[0][1], bR1, "0");    DSR(bv[1][1], bR1, "2048");
    DSR(bv[2][1], bR1, "4096"); DSR(bv[3][1], bR1, "6144");
    LOADAV(avA, "0", "2048");
    if (t < 31) { gload16(pA00, lds + dA00); gload16(pA01, lds + dA01); }
    LOADAV(avB, "4096", "6144");
    WAITLG(4);                       // bv + avA done; avB in flight
    MFMA_Q(0, avA);
    // ---- q1: stage A1(t+1); prefetch avA q2
    if (t < 31) { gload16(pA10, lds + dA10); gload16(pA11, lds + dA11); }
    LOADAV(avA, "8192", "10240");
    WAITLG(4);                       // avB done; avA(q2) in flight
    MFMA_Q(1, avB);
    BAR();   // mid-tile: all waves' bv consumed -> B-space(c) writable
    // ---- q2: stage B0(t+2); prefetch avB q3
    if (t < 30) { gload16(pB00, lds + dB00); gload16(pB01, lds + dB01); }
    LOADAV(avB, "12288", "14336");
    WAITLG(4);                       // avA(q2) done; avB(q3) in flight
    MFMA_Q(2, avA);
    // ---- q3: stage B1(t+2); counted vmcnt; flip
    if (t < 30) { gload16(pB10, lds + dB10); gload16(pB11, lds + dB11); }
    WAITLG(0);                       // avB(q3) done
    MFMA_Q(3, avB);
    if (t < 30)       { asm volatile("s_waitcnt vmcnt(4)" ::: "memory"); }
    else if (t == 30) { asm volatile("s_waitcnt vmcnt(0)" ::: "memory"); }
    SB();
    BAR();   // boundary: tile t+1 fully landed, flip buffer
    aR0 ^= 65536; aR1 ^= 65536; bR0 ^= 65536; bR1 ^= 65536;
    dA00 ^= 65536; dA01 ^= 65536; dA10 ^= 65536; dA11 ^= 65536;
    dB00 ^= 65536; dB01 ^= 65536; dB10 ^= 65536; dB11 ^= 65536;
    pA00 += 64; pA01 += 64; pA10 += 64; pA11 += 64;
    pB00 += 64; pB01 += 64; pB10 += 64; pB11 += 64;
  }

  // epilogue: per-row (max, sum-exp) over this wave's 64 cols + chosen gather
  // C/D layout: col = lane&15, row = (lane>>4)*4 + reg
  const int chunk = (bn << 2) | wn;
  const int colb = n0 + (wn << 6) + ln;
#pragma unroll
  for (int mi = 0; mi < 8; ++mi) {
#pragma unroll
    for (int rr = 0; rr < 4; ++rr) {
      const int row = m0 + (wm << 7) + (mi << 4) + (g4 << 2) + rr;
      float v0 = acc[mi][0][rr], v1 = acc[mi][1][rr];
      float v2 = acc[mi][2][rr], v3 = acc[mi][3][rr];
      float mx = fmaxf(fmaxf(v0, v1), fmaxf(v2, v3));
#pragma unroll
      for (int o = 1; o < 16; o <<= 1) mx = fmaxf(mx, __shfl_xor(mx, o, 64));
      float s = __expf(v0 - mx) + __expf(v1 - mx) + __expf(v2 - mx) + __expf(v3 - mx);
#pragma unroll
      for (int o = 1; o < 16; o <<= 1) s += __shfl_xor(s, o, 64);
      if (ln == 0) partials[(size_t)row * NCHUNK + chunk] = make_float2(mx, s);
      const int cc = chosen[row];   // -1 on pad rows -> never matches
      if (cc == colb)      chlog[row] = v0;
      if (cc == colb + 16) chlog[row] = v1;
      if (cc == colb + 32) chlog[row] = v2;
      if (cc == colb + 48) chlog[row] = v3;
    }
  }
#undef MFMA_Q
#undef LOADAV
}

// ---------- kernel 5: combine partials -> lse -> logps -> loss terms ----------
__global__ void reduce_lse(const float2* __restrict__ partials,
                           const float* __restrict__ chlog,
                           const float* __restrict__ oldlp,
                           const int* __restrict__ labels,
                           const float* __restrict__ adv,
                           float* __restrict__ out, float* __restrict__ accum) {
  const int wid = threadIdx.x >> 6, l = threadIdx.x & 63;
  const int row = blockIdx.x * 4 + wid;        // 1023*4 = 4092 exactly
  float M = -INFINITY, S = 0.f;
  for (int c = l; c < NCHUNK; c += 64) {
    float2 p = partials[(size_t)row * NCHUNK + c];
    float Mn = fmaxf(M, p.x);
    S = S * __expf(M - Mn) + p.y * __expf(p.x - Mn);
    M = Mn;
  }
#pragma unroll
  for (int o = 1; o < 64; o <<= 1) {
    float Mo = __shfl_xor(M, o, 64), So = __shfl_xor(S, o, 64);
    float Mn = fmaxf(M, Mo);
    S = S * __expf(M - Mn) + So * __expf(Mo - Mn);
    M = Mn;
  }
  if (l == 0) {
    float lse = M + __logf(S);
    float ptl = chlog[row] - lse;
    out[1 + row] = ptl;
    int b = row / 1023, t = row % 1023;
    float a = adv[b];
    float ratio = __expf(ptl - oldlp[row]);
    float l1 = ratio * a;
    float l2 = fminf(fmaxf(ratio, 0.8f), 1.3f) * a;
    float mk = (float)labels[b * 1024 + t + 1];
    atomicAdd(accum + 0, -fminf(l1, l2) * mk);
    atomicAdd(accum + 1, mk);
  }
}

__global__ void finalize_k(const float* __restrict__ accum, float* __restrict__ out) {
  out[0] = accum[0] / accum[1];
}

// ---------- launch ----------
extern "C" void kernel_launch(void* const* d_in, const int* in_sizes, int n_in,
                              void* d_out, int out_size, void* d_ws, size_t ws_size,
                              hipStream_t stream) {
  const float* hs     = (const float*)d_in[0];   // (4,1024,2048)
  const float* W      = (const float*)d_in[1];   // (2048,32768)
  const int*   ids    = (const int*)d_in[2];     // (4,1024)
  const int*   labels = (const int*)d_in[3];     // (4,1024)
  const float* adv    = (const float*)d_in[4];   // (4,)
  const float* oldlp  = (const float*)d_in[5];   // (4,1023)
  float* out = (float*)d_out;                    // [loss, 4092 x per_token_logps]

  char* ws = (char*)d_ws;
  u16*    WT       = (u16*)ws;                         // 134,217,728 B
  u16*    hb       = (u16*)(ws + 134217728);           //  16,777,216 B
  float2* partials = (float2*)(ws + 150994944);        //  16,777,216 B
  float*  chlog    = (float*)(ws + 167772160);         //      16,384 B
  int*    chosen   = (int*)(ws + 167788544);           //      16,384 B
  float*  accum    = (float*)(ws + 167804928);         //           8 B

  (void)hipFuncSetAttribute((const void*)gemm_lse,
                            hipFuncAttributeMaxDynamicSharedMemorySize, 131072);

  init_k<<<16, 256, 0, stream>>>(ids, chosen, accum);
  conv_h<<<8192, 256, 0, stream>>>(hs, hb);
  transpose_w<<<dim3(512, 32), 256, 0, stream>>>(W, WT);
  gemm_lse<<<2048, 512, 131072, stream>>>(hb, WT, chosen, partials, chlog);
  reduce_lse<<<1023, 256, 0, stream>>>(partials, chlog, oldlp, labels, adv, out, accum);
  finalize_k<<<1, 1, 0, stream>>>(accum, out);
}

// Round 7
// 618.903 us; speedup vs baseline: 1.5261x; 1.1615x over previous
//
#include <hip/hip_runtime.h>
#include <hip/hip_bf16.h>

typedef unsigned short u16;
typedef unsigned char u8;
typedef unsigned long long u64;
typedef __attribute__((ext_vector_type(4))) int i32x4;
typedef __attribute__((ext_vector_type(8))) int i32x8;
typedef __attribute__((ext_vector_type(4))) float f32x4;

#define NROWS 4092      // 4 * 1023 valid token rows
#define NROWS_PAD 4096
#define DDIM 2048
#define VDIM 32768
#define NCHUNK 512      // 64-wide vocab chunks per row
#define SC8 0x7F7F7F7F  // e8m0 scale = 1.0 in all four bytes

// ---------- helpers ----------
// RNE fp32 -> OCP e4m3fn (manual, incl. denormals + saturation to 448)
__device__ __forceinline__ u8 f2fp8(float f) {
  union { float f; unsigned u; } v; v.f = f;
  unsigned s = (v.u >> 24) & 0x80u;
  unsigned a = v.u & 0x7FFFFFFFu;
  if (a >= 0x43E80000u) return (u8)(s | 0x7E);   // |f| >= 464 -> 448
  int e = (int)(a >> 23) - 127;
  unsigned m = a & 0x7FFFFFu;
  if (e < -6) {                                   // denormal target
    unsigned full = m | 0x800000u;
    int sh = 20 + (-6 - e);
    if (sh > 31) return (u8)s;
    unsigned q = full >> sh;
    unsigned rem = full & ((1u << sh) - 1u), half = 1u << (sh - 1);
    q += (rem > half || (rem == half && (q & 1u)));
    return (u8)(s | q);                           // q==8 rolls into E=1 correctly
  }
  unsigned q = m >> 20, rem = m & 0xFFFFFu;
  q += (rem > 0x80000u || (rem == 0x80000u && (q & 1u)));
  unsigned bits = (((unsigned)(e + 7)) << 3) + q; // mantissa carry rolls exponent
  if (bits >= 0x7Fu) bits = 0x7Eu;
  return (u8)(s | bits);
}

__device__ __forceinline__ void gload16(const void* g, void* l) {
  using gp_t = const __attribute__((address_space(1))) unsigned*;
  using lp_t = __attribute__((address_space(3))) unsigned*;
  __builtin_amdgcn_global_load_lds((gp_t)g, (lp_t)(unsigned)(unsigned long long)l,
                                   16, 0, 0);
}

#define BAR() __builtin_amdgcn_s_barrier()
#define SB()  __builtin_amdgcn_sched_barrier(0)
#define DSR(d, a, o) asm volatile("ds_read_b128 %0, %1 offset:" o : "=&v"(d) : "v"(a))
#define WAITLG(n) do { asm volatile("s_waitcnt lgkmcnt(" #n ")" ::: "memory"); SB(); } while (0)
#define SHUF(a, b) __builtin_shufflevector(a, b, 0, 1, 2, 3, 4, 5, 6, 7)

// ---------- kernel 1: chosen ids (padded) + zero chlog/accum ----------
__global__ void init_k(const int* __restrict__ ids, int* __restrict__ chosen,
                       float* __restrict__ chlog, float* __restrict__ accum) {
  int i = blockIdx.x * 256 + threadIdx.x;
  if (i < NROWS_PAD) {
    int v = -1;
    if (i < NROWS) { int b = i / 1023, t = i % 1023; v = ids[b * 1024 + t + 1]; }
    chosen[i] = v;
    chlog[i] = 0.f;
  }
  if (i < 2) accum[i] = 0.f;
}

// ---------- kernel 2: h fp32 -> fp8 e4m3 (x16), row-remapped, padded ------
__global__ void conv_h(const float* __restrict__ hs, u8* __restrict__ h8) {
  int idx = blockIdx.x * 256 + threadIdx.x;   // 1,048,576 threads, 8 elems each
  int row = idx >> 8;
  int c8 = (idx & 255) << 3;
  u64 o = 0;
  if (row < NROWS) {
    int b = row / 1023, t = row % 1023;
    const float* p = hs + (size_t)((b << 10) + t) * DDIM + c8;
    float4 x = *(const float4*)p, y = *(const float4*)(p + 4);
    o = (u64)f2fp8(x.x * 16.f)        | ((u64)f2fp8(x.y * 16.f) << 8) |
        ((u64)f2fp8(x.z * 16.f) << 16) | ((u64)f2fp8(x.w * 16.f) << 24) |
        ((u64)f2fp8(y.x * 16.f) << 32) | ((u64)f2fp8(y.y * 16.f) << 40) |
        ((u64)f2fp8(y.z * 16.f) << 48) | ((u64)f2fp8(y.w * 16.f) << 56);
  }
  *(u64*)(h8 + (size_t)row * DDIM + c8) = o;
}

// ---------- kernel 3: W (D x V fp32) -> W^T (V x D fp8 e4m3 x64)
//            + EXACT fp32 chosen-logit partial dots (atomicAdd into chlog) ---
__global__ void transpose_w(const float* __restrict__ W, u8* __restrict__ WT8,
                            const float* __restrict__ hs,
                            const int* __restrict__ chosen,
                            float* __restrict__ chlog) {
  __shared__ float t32[64][65];     // [d][v] fp32 tile (exact dots)
  __shared__ u8 t8[64][68];         // [d][v] quantized
  __shared__ int mlist[256];
  __shared__ int mcount;
  int v0 = blockIdx.x << 6, d0 = blockIdx.y << 6;
  int tid = threadIdx.x;
  if (tid == 0) mcount = 0;
  __syncthreads();
  int vi = (tid & 15) << 2, dl = tid >> 4;
#pragma unroll
  for (int i = 0; i < 4; ++i) {
    int d = dl + (i << 4);
    float4 w = *(const float4*)(W + (size_t)(d0 + d) * VDIM + v0 + vi);
    t32[d][vi + 0] = w.x; t32[d][vi + 1] = w.y;
    t32[d][vi + 2] = w.z; t32[d][vi + 3] = w.w;
    t8[d][vi + 0] = f2fp8(w.x * 64.f); t8[d][vi + 1] = f2fp8(w.y * 64.f);
    t8[d][vi + 2] = f2fp8(w.z * 64.f); t8[d][vi + 3] = f2fp8(w.w * 64.f);
  }
  // scan chosen[] for ids in [v0, v0+64)
#pragma unroll
  for (int j = 0; j < 16; ++j) {
    int r = tid + (j << 8);
    int c = chosen[r];
    if ((unsigned)(c - v0) < 64u) {
      int i = atomicAdd(&mcount, 1);
      if (i < 256) mlist[i] = (r << 8) | (c - v0);
    }
  }
  __syncthreads();
  // transposed fp8 write: wave-coalesced 16B chunks
  int vr = tid >> 2, dc = (tid & 3) << 4;
  union { u8 b[16]; ulonglong2 q; } u;
#pragma unroll
  for (int k = 0; k < 16; ++k) u.b[k] = t8[dc + k][vr];
  *(ulonglong2*)(WT8 + (size_t)(v0 + vr) * DDIM + d0 + dc) = u.q;
  // exact chosen dots: one wave per match
  int lane = tid & 63, wv = tid >> 6;
  int mc = mcount < 256 ? mcount : 256;
  for (int m = wv; m < mc; m += 4) {
    int e = mlist[m];
    int r = e >> 8, cv = e & 255;
    int b = r / 1023, tt = r % 1023;
    float s = hs[(size_t)((b << 10) + tt) * DDIM + d0 + lane] * t32[lane][cv];
#pragma unroll
    for (int o = 1; o < 64; o <<= 1) s += __shfl_xor(s, o, 64);
    if (lane == 0) atomicAdd(chlog + r, s);
  }
}

// ---------- kernel 4: 256x256 fp8 GEMM (mfma_scale 16x16x128) + online-LSE -
// A8: [4096][2048] fp8 (x16, zero-padded rows), Bt8: [32768][2048] fp8 (x64)
// LDS (128 KiB): [buf][A/B][half(128 rows)][128 B/row] (= 128 K-elems, BK=128)
// Byte layout, staging, XOR swizzle, counted-vmcnt chain identical to the
// verified bf16 R6 kernel; 16 K-tiles; logits carry x1024, epilogue divides.
__global__ __launch_bounds__(512, 2) void gemm_lse(
    const u8* __restrict__ A, const u8* __restrict__ Bt,
    float2* __restrict__ partials) {
  extern __shared__ u16 smem[];
  char* lds = (char*)smem;
  const unsigned lbase = (unsigned)(unsigned long long)lds;

  const int tid = threadIdx.x;
  const int l = tid & 63;
  const int wid = tid >> 6;                // 8 waves
  const int wm = wid >> 2, wn = wid & 3;   // 2 x 4
  const int ln = l & 15;
  const int g4 = l >> 4;
  const int xr = ln & 7;

  // XCD-bijective swizzle (2048 % 8 == 0)
  int bid = blockIdx.x;
  int id = ((bid & 7) << 8) | (bid >> 3);
  int bm = id & 15;                  // 0..15
  int bn = id >> 4;                  // 0..127
  const int m0 = bm << 8, n0 = bn << 8;

  const u8* Ab = A + (size_t)m0 * DDIM;
  const u8* Bb = Bt + (size_t)n0 * DDIM;

  // swizzled LDS read bases: slot = ((g4<<1)|u) ^ xr, 16B units
  unsigned aR0 = lbase + (wm << 14) + (ln << 7) + ((((g4 << 1) | 0) ^ xr) << 4);
  unsigned aR1 = lbase + (wm << 14) + (ln << 7) + ((((g4 << 1) | 1) ^ xr) << 4);
  unsigned bR0 = lbase + 32768 + ((wn >> 1) << 14) + ((((wn & 1) << 6) | ln) << 7) + ((((g4 << 1) | 0) ^ xr) << 4);
  unsigned bR1 = lbase + 32768 + ((wn >> 1) << 14) + ((((wn & 1) << 6) | ln) << 7) + ((((g4 << 1) | 1) ^ xr) << 4);

  // stage LDS dests (init: A->buf1, B->buf0; flip ^0x10000/tile)
  unsigned dA00 = 65536 + (wid << 10),         dA01 = 65536 + ((8 + wid) << 10);
  unsigned dA10 = 65536 + 16384 + (wid << 10), dA11 = 65536 + 16384 + ((8 + wid) << 10);
  unsigned dB00 = 32768 + (wid << 10),         dB01 = 32768 + ((8 + wid) << 10);
  unsigned dB10 = 49152 + (wid << 10),         dB11 = 49152 + ((8 + wid) << 10);

  // stage global pointers (pre-permuted source; advance +128 B/tile)
  const int srow = l >> 3;
  const int sel = ((l & 7) ^ srow) << 4;       // bytes
  const int r0 = (wid << 3) | srow;
  const int r1 = ((8 + wid) << 3) | srow;
  const u8* pA00 = Ab + (size_t)r0 * DDIM + sel + 128;          // A(1) half0
  const u8* pA01 = Ab + (size_t)r1 * DDIM + sel + 128;
  const u8* pA10 = Ab + (size_t)(128 + r0) * DDIM + sel + 128;  // A(1) half1
  const u8* pA11 = Ab + (size_t)(128 + r1) * DDIM + sel + 128;
  const u8* pB00 = Bb + (size_t)r0 * DDIM + sel + 256;          // B(2) half0
  const u8* pB01 = Bb + (size_t)r1 * DDIM + sel + 256;
  const u8* pB10 = Bb + (size_t)(128 + r0) * DDIM + sel + 256;  // B(2) half1
  const u8* pB11 = Bb + (size_t)(128 + r1) * DDIM + sel + 256;

#define MFMA_PH(q, A0, A1) do {                                                \
    __builtin_amdgcn_s_setprio(1);                                             \
    _Pragma("unroll")                                                          \
    for (int _ni = 0; _ni < 4; ++_ni)                                          \
      acc[(q) * 2][_ni] = __builtin_amdgcn_mfma_scale_f32_16x16x128_f8f6f4(    \
          (A0), bf[_ni], acc[(q) * 2][_ni], 0, 0, 0, SC8, 0, SC8);             \
    _Pragma("unroll")                                                          \
    for (int _ni = 0; _ni < 4; ++_ni)                                          \
      acc[(q) * 2 + 1][_ni] = __builtin_amdgcn_mfma_scale_f32_16x16x128_f8f6f4(\
          (A1), bf[_ni], acc[(q) * 2 + 1][_ni], 0, 0, 0, SC8, 0, SC8);         \
    __builtin_amdgcn_s_setprio(0);                                             \
  } while (0)

  f32x4 acc[8][4] = {};

  // prologue: A(0),B(0) -> buf0; B(1) -> buf1; wait tile0, leave B(1) in flight
  gload16(pA00 - 128, lds + (dA00 ^ 65536)); gload16(pA01 - 128, lds + (dA01 ^ 65536));
  gload16(pA10 - 128, lds + (dA10 ^ 65536)); gload16(pA11 - 128, lds + (dA11 ^ 65536));
  gload16(pB00 - 256, lds + dB00); gload16(pB01 - 256, lds + dB01);
  gload16(pB10 - 256, lds + dB10); gload16(pB11 - 256, lds + dB11);
  gload16(pB00 - 128, lds + (dB00 ^ 65536)); gload16(pB01 - 128, lds + (dB01 ^ 65536));
  gload16(pB10 - 128, lds + (dB10 ^ 65536)); gload16(pB11 - 128, lds + (dB11 ^ 65536));
  asm volatile("s_waitcnt vmcnt(4)" ::: "memory"); SB();
  BAR();

  for (int t = 0; t < 16; ++t) {
    i32x4 blo0, bhi0, blo1, bhi1, blo2, bhi2, blo3, bhi3;
    i32x4 alo0, ahi0, alo1, ahi1, nlo0, nhi0, nlo1, nhi1;
    // ---- q0: bv(8) + avA(mi0,1); stage A0(t+1); prefetch av(mi2,3)
    DSR(blo0, bR0, "0");    DSR(bhi0, bR1, "0");
    DSR(blo1, bR0, "2048"); DSR(bhi1, bR1, "2048");
    DSR(blo2, bR0, "4096"); DSR(bhi2, bR1, "4096");
    DSR(blo3, bR0, "6144"); DSR(bhi3, bR1, "6144");
    DSR(alo0, aR0, "0");    DSR(ahi0, aR1, "0");
    DSR(alo1, aR0, "2048"); DSR(ahi1, aR1, "2048");
    if (t < 15) { gload16(pA00, lds + dA00); gload16(pA01, lds + dA01); }
    DSR(nlo0, aR0, "4096"); DSR(nhi0, aR1, "4096");
    DSR(nlo1, aR0, "6144"); DSR(nhi1, aR1, "6144");
    WAITLG(4);                       // bv + av(mi0,1) done; prefetch in flight
    i32x8 bf[4];
    bf[0] = SHUF(blo0, bhi0); bf[1] = SHUF(blo1, bhi1);
    bf[2] = SHUF(blo2, bhi2); bf[3] = SHUF(blo3, bhi3);
    MFMA_PH(0, SHUF(alo0, ahi0), SHUF(alo1, ahi1));
    // ---- q1: stage A1(t+1); prefetch av(mi4,5)
    if (t < 15) { gload16(pA10, lds + dA10); gload16(pA11, lds + dA11); }
    DSR(alo0, aR0, "8192");  DSR(ahi0, aR1, "8192");
    DSR(alo1, aR0, "10240"); DSR(ahi1, aR1, "10240");
    WAITLG(4);
    MFMA_PH(1, SHUF(nlo0, nhi0), SHUF(nlo1, nhi1));
    BAR();   // mid-tile: all waves' bv consumed -> B-space(c) writable
    // ---- q2: stage B0(t+2); prefetch av(mi6,7)
    if (t < 14) { gload16(pB00, lds + dB00); gload16(pB01, lds + dB01); }
    DSR(nlo0, aR0, "12288"); DSR(nhi0, aR1, "12288");
    DSR(nlo1, aR0, "14336"); DSR(nhi1, aR1, "14336");
    WAITLG(4);
    MFMA_PH(2, SHUF(alo0, ahi0), SHUF(alo1, ahi1));
    // ---- q3: stage B1(t+2); counted vmcnt; flip
    if (t < 14) { gload16(pB10, lds + dB10); gload16(pB11, lds + dB11); }
    WAITLG(0);
    MFMA_PH(3, SHUF(nlo0, nhi0), SHUF(nlo1, nhi1));
    if (t < 14)       { asm volatile("s_waitcnt vmcnt(4)" ::: "memory"); }
    else if (t == 14) { asm volatile("s_waitcnt vmcnt(0)" ::: "memory"); }
    SB();
    BAR();   // boundary: tile t+1 fully landed, flip buffer
    aR0 ^= 65536; aR1 ^= 65536; bR0 ^= 65536; bR1 ^= 65536;
    dA00 ^= 65536; dA01 ^= 65536; dA10 ^= 65536; dA11 ^= 65536;
    dB00 ^= 65536; dB01 ^= 65536; dB10 ^= 65536; dB11 ^= 65536;
    pA00 += 128; pA01 += 128; pA10 += 128; pA11 += 128;
    pB00 += 128; pB01 += 128; pB10 += 128; pB11 += 128;
  }

  // epilogue: per-row (max, sum-exp) over this wave's 64 cols (scale /1024)
  // C/D layout: col = lane&15, row = (lane>>4)*4 + reg
  const int chunk = (bn << 2) | wn;
#pragma unroll
  for (int mi = 0; mi < 8; ++mi) {
#pragma unroll
    for (int rr = 0; rr < 4; ++rr) {
      const int row = m0 + (wm << 7) + (mi << 4) + (g4 << 2) + rr;
      float v0 = acc[mi][0][rr] * 0.0009765625f;
      float v1 = acc[mi][1][rr] * 0.0009765625f;
      float v2 = acc[mi][2][rr] * 0.0009765625f;
      float v3 = acc[mi][3][rr] * 0.0009765625f;
      float mx = fmaxf(fmaxf(v0, v1), fmaxf(v2, v3));
#pragma unroll
      for (int o = 1; o < 16; o <<= 1) mx = fmaxf(mx, __shfl_xor(mx, o, 64));
      float s = __expf(v0 - mx) + __expf(v1 - mx) + __expf(v2 - mx) + __expf(v3 - mx);
#pragma unroll
      for (int o = 1; o < 16; o <<= 1) s += __shfl_xor(s, o, 64);
      if (ln == 0) partials[(size_t)row * NCHUNK + chunk] = make_float2(mx, s);
    }
  }
#undef MFMA_PH
}

// ---------- kernel 5: combine partials -> lse -> logps -> loss terms ----------
__global__ void reduce_lse(const float2* __restrict__ partials,
                           const float* __restrict__ chlog,
                           const float* __restrict__ oldlp,
                           const int* __restrict__ labels,
                           const float* __restrict__ adv,
                           float* __restrict__ out, float* __restrict__ accum) {
  const int wid = threadIdx.x >> 6, l = threadIdx.x & 63;
  const int row = blockIdx.x * 4 + wid;        // 1023*4 = 4092 exactly
  float M = -INFINITY, S = 0.f;
  for (int c = l; c < NCHUNK; c += 64) {
    float2 p = partials[(size_t)row * NCHUNK + c];
    float Mn = fmaxf(M, p.x);
    S = S * __expf(M - Mn) + p.y * __expf(p.x - Mn);
    M = Mn;
  }
#pragma unroll
  for (int o = 1; o < 64; o <<= 1) {
    float Mo = __shfl_xor(M, o, 64), So = __shfl_xor(S, o, 64);
    float Mn = fmaxf(M, Mo);
    S = S * __expf(M - Mn) + So * __expf(Mo - Mn);
    M = Mn;
  }
  if (l == 0) {
    float lse = M + __logf(S);
    float ptl = chlog[row] - lse;
    out[1 + row] = ptl;
    int b = row / 1023, t = row % 1023;
    float a = adv[b];
    float ratio = __expf(ptl - oldlp[row]);
    float l1 = ratio * a;
    float l2 = fminf(fmaxf(ratio, 0.8f), 1.3f) * a;
    float mk = (float)labels[b * 1024 + t + 1];
    atomicAdd(accum + 0, -fminf(l1, l2) * mk);
    atomicAdd(accum + 1, mk);
  }
}

__global__ void finalize_k(const float* __restrict__ accum, float* __restrict__ out) {
  out[0] = accum[0] / accum[1];
}

// ---------- launch ----------
extern "C" void kernel_launch(void* const* d_in, const int* in_sizes, int n_in,
                              void* d_out, int out_size, void* d_ws, size_t ws_size,
                              hipStream_t stream) {
  const float* hs     = (const float*)d_in[0];   // (4,1024,2048)
  const float* W      = (const float*)d_in[1];   // (2048,32768)
  const int*   ids    = (const int*)d_in[2];     // (4,1024)
  const int*   labels = (const int*)d_in[3];     // (4,1024)
  const float* adv    = (const float*)d_in[4];   // (4,)
  const float* oldlp  = (const float*)d_in[5];   // (4,1023)
  float* out = (float*)d_out;                    // [loss, 4092 x per_token_logps]

  // ws layout (~92.3 MB)
  char* ws = (char*)d_ws;
  u8*     WT8      = (u8*)ws;                          //  67,108,864 B
  u8*     h8       = (u8*)(ws + 67108864);             //   8,388,608 B
  float2* partials = (float2*)(ws + 75497472);         //  16,777,216 B
  float*  chlog    = (float*)(ws + 92274688);          //      16,384 B
  int*    chosen   = (int*)(ws + 92291072);            //      16,384 B
  float*  accum    = (float*)(ws + 92307456);          //           8 B

  (void)hipFuncSetAttribute((const void*)gemm_lse,
                            hipFuncAttributeMaxDynamicSharedMemorySize, 131072);

  init_k<<<16, 256, 0, stream>>>(ids, chosen, chlog, accum);
  conv_h<<<4096, 256, 0, stream>>>(hs, h8);
  transpose_w<<<dim3(512, 32), 256, 0, stream>>>(W, WT8, hs, chosen, chlog);
  gemm_lse<<<2048, 512, 131072, stream>>>(h8, WT8, partials);
  reduce_lse<<<1023, 256, 0, stream>>>(partials, chlog, oldlp, labels, adv, out, accum);
  finalize_k<<<1, 1, 0, stream>>>(accum, out);
}

// Round 8
// 584.793 us; speedup vs baseline: 1.6151x; 1.0583x over previous
//
#include <hip/hip_runtime.h>
#include <hip/hip_bf16.h>

typedef unsigned short u16;
typedef unsigned char u8;
typedef unsigned long long u64;
typedef __attribute__((ext_vector_type(4))) int i32x4;
typedef __attribute__((ext_vector_type(8))) int i32x8;
typedef __attribute__((ext_vector_type(4))) float f32x4;

#define NROWS 4092      // 4 * 1023 valid token rows
#define NROWS_PAD 4096
#define DDIM 2048
#define VDIM 32768
#define NCHUNK 512      // 64-wide vocab chunks per row
#define SC8 0x7F7F7F7F  // e8m0 scale = 1.0 in all four bytes

// ---------- helpers ----------
// RNE fp32 -> OCP e4m3fn (manual, incl. denormals + saturation to 448)
__device__ __forceinline__ u8 f2fp8(float f) {
  union { float f; unsigned u; } v; v.f = f;
  unsigned s = (v.u >> 24) & 0x80u;
  unsigned a = v.u & 0x7FFFFFFFu;
  if (a >= 0x43E80000u) return (u8)(s | 0x7E);   // |f| >= 464 -> 448
  int e = (int)(a >> 23) - 127;
  unsigned m = a & 0x7FFFFFu;
  if (e < -6) {                                   // denormal target
    unsigned full = m | 0x800000u;
    int sh = 20 + (-6 - e);
    if (sh > 31) return (u8)s;
    unsigned q = full >> sh;
    unsigned rem = full & ((1u << sh) - 1u), half = 1u << (sh - 1);
    q += (rem > half || (rem == half && (q & 1u)));
    return (u8)(s | q);
  }
  unsigned q = m >> 20, rem = m & 0xFFFFFu;
  q += (rem > 0x80000u || (rem == 0x80000u && (q & 1u)));
  unsigned bits = (((unsigned)(e + 7)) << 3) + q;
  if (bits >= 0x7Fu) bits = 0x7Eu;
  return (u8)(s | bits);
}

__device__ __forceinline__ void gload16(const void* g, void* l) {
  using gp_t = const __attribute__((address_space(1))) unsigned*;
  using lp_t = __attribute__((address_space(3))) unsigned*;
  __builtin_amdgcn_global_load_lds((gp_t)g, (lp_t)(unsigned)(unsigned long long)l,
                                   16, 0, 0);
}

#define BAR() __builtin_amdgcn_s_barrier()
#define SB()  __builtin_amdgcn_sched_barrier(0)
#define DSR(d, a, o) asm volatile("ds_read_b128 %0, %1 offset:" o : "=&v"(d) : "v"(a))
#define WAITLG(n) do { asm volatile("s_waitcnt lgkmcnt(" #n ")" ::: "memory"); SB(); } while (0)
#define SHUF(a, b) __builtin_shufflevector(a, b, 0, 1, 2, 3, 4, 5, 6, 7)

// ---------- kernel 1: chosen ids (padded) + zero chlog/accum ----------
__global__ void init_k(const int* __restrict__ ids, int* __restrict__ chosen,
                       float* __restrict__ chlog, float* __restrict__ accum) {
  int i = blockIdx.x * 256 + threadIdx.x;
  if (i < NROWS_PAD) {
    int v = -1;
    if (i < NROWS) { int b = i / 1023, t = i % 1023; v = ids[b * 1024 + t + 1]; }
    chosen[i] = v;
    chlog[i] = 0.f;
  }
  if (i < 2) accum[i] = 0.f;
}

// ---------- kernel 1b: bucket chosen ids by 64-wide vocab tile ----------
__global__ void bucket_k(const int* __restrict__ chosen,
                         int* __restrict__ boff, int* __restrict__ bent) {
  __shared__ int cnt[512];
  __shared__ int base[512];
  int tid = threadIdx.x;             // 512 threads
  cnt[tid] = 0;
  __syncthreads();
  int loc[8], tile[8];
#pragma unroll
  for (int j = 0; j < 8; ++j) {
    int r = tid + (j << 9);
    int c = chosen[r];
    int ti = (c < 0) ? 512 : (c >> 6);
    tile[j] = ti;
    loc[j] = (ti < 512) ? atomicAdd(&cnt[ti], 1) : 0;
  }
  __syncthreads();
  if (tid == 0) {
    int s = 0;
    for (int i = 0; i < 512; ++i) { base[i] = s; s += cnt[i]; }
  }
  __syncthreads();
  boff[tid] = base[tid];
  if (tid == 511) boff[512] = base[511] + cnt[511];
#pragma unroll
  for (int j = 0; j < 8; ++j) {
    int r = tid + (j << 9);
    if (tile[j] < 512) bent[base[tile[j]] + loc[j]] = (r << 6) | (chosen[r] & 63);
  }
}

// ---------- kernel 2: h fp32 -> fp8 e4m3 (x16), row-remapped, padded ------
__global__ void conv_h(const float* __restrict__ hs, u8* __restrict__ h8) {
  int idx = blockIdx.x * 256 + threadIdx.x;   // 1,048,576 threads, 8 elems each
  int row = idx >> 8;
  int c8 = (idx & 255) << 3;
  u64 o = 0;
  if (row < NROWS) {
    int b = row / 1023, t = row % 1023;
    const float* p = hs + (size_t)((b << 10) + t) * DDIM + c8;
    float4 x = *(const float4*)p, y = *(const float4*)(p + 4);
    o = (u64)f2fp8(x.x * 16.f)        | ((u64)f2fp8(x.y * 16.f) << 8) |
        ((u64)f2fp8(x.z * 16.f) << 16) | ((u64)f2fp8(x.w * 16.f) << 24) |
        ((u64)f2fp8(y.x * 16.f) << 32) | ((u64)f2fp8(y.y * 16.f) << 40) |
        ((u64)f2fp8(y.z * 16.f) << 48) | ((u64)f2fp8(y.w * 16.f) << 56);
  }
  *(u64*)(h8 + (size_t)row * DDIM + c8) = o;
}

// ---------- kernel 3: W (D x V fp32) -> W^T (V x D fp8 e4m3 x64)
//            + EXACT fp32 chosen-logit partial dots (atomicAdd into chlog) ---
__global__ void transpose_w(const float* __restrict__ W, u8* __restrict__ WT8,
                            const float* __restrict__ hs,
                            const int* __restrict__ boff,
                            const int* __restrict__ bent,
                            float* __restrict__ chlog) {
  __shared__ float t32[64][65];     // [d][v] fp32 tile (exact dots)
  __shared__ u8 t8[64][68];         // [d][v] quantized
  int v0 = blockIdx.x << 6, d0 = blockIdx.y << 6;
  int tid = threadIdx.x;
  int vi = (tid & 15) << 2, dl = tid >> 4;
#pragma unroll
  for (int i = 0; i < 4; ++i) {
    int d = dl + (i << 4);
    float4 w = *(const float4*)(W + (size_t)(d0 + d) * VDIM + v0 + vi);
    t32[d][vi + 0] = w.x; t32[d][vi + 1] = w.y;
    t32[d][vi + 2] = w.z; t32[d][vi + 3] = w.w;
    t8[d][vi + 0] = f2fp8(w.x * 64.f); t8[d][vi + 1] = f2fp8(w.y * 64.f);
    t8[d][vi + 2] = f2fp8(w.z * 64.f); t8[d][vi + 3] = f2fp8(w.w * 64.f);
  }
  __syncthreads();
  // transposed fp8 write: wave-coalesced 16B chunks
  int vr = tid >> 2, dc = (tid & 3) << 4;
  union { u8 b[16]; ulonglong2 q; } u;
#pragma unroll
  for (int k = 0; k < 16; ++k) u.b[k] = t8[dc + k][vr];
  *(ulonglong2*)(WT8 + (size_t)(v0 + vr) * DDIM + d0 + dc) = u.q;
  // exact chosen dots from the pre-bucketed list: one wave per match
  int m0 = boff[blockIdx.x], m1 = boff[blockIdx.x + 1];
  int lane = tid & 63, wv = tid >> 6;
  for (int m = m0 + wv; m < m1; m += 4) {
    int e = bent[m];
    int r = e >> 6, cv = e & 63;
    int b = r / 1023, tt = r % 1023;
    float s = hs[(size_t)((b << 10) + tt) * DDIM + d0 + lane] * t32[lane][cv];
#pragma unroll
    for (int o = 1; o < 64; o <<= 1) s += __shfl_xor(s, o, 64);
    if (lane == 0) atomicAdd(chlog + r, s);
  }
}

// ---------- kernel 4: 256x256 fp8 GEMM (mfma_scale 16x16x128) + online-LSE -
// A8: [4096][2048] fp8 (x16, zero-padded rows), Bt8: [32768][2048] fp8 (x64)
// LDS (128 KiB): [buf][A/B][half(128 rows)][128 B/row], BK=128, 16 K-tiles.
// Register-diet addressing: staging = SGPR base (uniform tile/half offsets) +
// 2 lane voffsets; LDS dests = readfirstlane'd uniform ints. Schedule (DSR
// order, counted lgkmcnt/vmcnt, 2 barriers/tile) identical to R7.
__global__ __launch_bounds__(512, 2) void gemm_lse(
    const u8* __restrict__ A, const u8* __restrict__ Bt,
    float2* __restrict__ partials) {
  extern __shared__ u16 smem[];
  char* lds = (char*)smem;
  const unsigned lbase = (unsigned)(unsigned long long)lds;

  const int tid = threadIdx.x;
  const int l = tid & 63;
  const int wid = tid >> 6;                // 8 waves
  const int wm = wid >> 2, wn = wid & 3;   // 2 x 4
  const int ln = l & 15;
  const int g4 = l >> 4;
  const int xr = ln & 7;

  // XCD-bijective swizzle (2048 % 8 == 0)
  int bid = blockIdx.x;
  int id = ((bid & 7) << 8) | (bid >> 3);
  int bm = id & 15;                  // 0..15
  int bn = id >> 4;                  // 0..127
  const int m0 = bm << 8, n0 = bn << 8;

  const u8* Ab = A + (size_t)m0 * DDIM;
  const u8* Bb = Bt + (size_t)n0 * DDIM;

  // swizzled LDS read bases: slot = ((g4<<1)|u) ^ xr, 16B units
  unsigned aR0 = lbase + (wm << 14) + (ln << 7) + ((((g4 << 1) | 0) ^ xr) << 4);
  unsigned aR1 = lbase + (wm << 14) + (ln << 7) + ((((g4 << 1) | 1) ^ xr) << 4);
  unsigned bR0 = lbase + 32768 + ((wn >> 1) << 14) + ((((wn & 1) << 6) | ln) << 7) + ((((g4 << 1) | 0) ^ xr) << 4);
  unsigned bR1 = lbase + 32768 + ((wn >> 1) << 14) + ((((wn & 1) << 6) | ln) << 7) + ((((g4 << 1) | 1) ^ xr) << 4);

  // staging: lane voffsets (pre-permuted source), wave-uniform dest pieces
  const int srow = l >> 3;
  const unsigned selb = (unsigned)(((l & 7) ^ srow) << 4);   // bytes
  const unsigned voff0 = (unsigned)(((wid << 3) | srow) * 2048) + selb;       // rows 0..63
  const unsigned voff1 = (unsigned)((((8 + wid) << 3) | srow) * 2048) + selb; // rows 64..127
  const int w10 = wid << 10;

#define RFL(x) __builtin_amdgcn_readfirstlane((int)(x))
#define GLL(src, dst) gload16((src), lds + RFL(dst))

#define MFMA_PH(q, A0, A1) do {                                                \
    __builtin_amdgcn_s_setprio(1);                                             \
    _Pragma("unroll")                                                          \
    for (int _ni = 0; _ni < 4; ++_ni)                                          \
      acc[(q) * 2][_ni] = __builtin_amdgcn_mfma_scale_f32_16x16x128_f8f6f4(    \
          (A0), bf[_ni], acc[(q) * 2][_ni], 0, 0, 0, SC8, 0, SC8);             \
    _Pragma("unroll")                                                          \
    for (int _ni = 0; _ni < 4; ++_ni)                                          \
      acc[(q) * 2 + 1][_ni] = __builtin_amdgcn_mfma_scale_f32_16x16x128_f8f6f4(\
          (A1), bf[_ni], acc[(q) * 2 + 1][_ni], 0, 0, 0, SC8, 0, SC8);         \
    __builtin_amdgcn_s_setprio(0);                                             \
  } while (0)

  f32x4 acc[8][4] = {};

  // prologue: A(0),B(0) -> buf0; B(1) -> buf1; wait tile0, leave B(1) in flight
  GLL(Ab + voff0, w10);                    GLL(Ab + voff1, w10 + 8192);
  GLL(Ab + 262144 + voff0, w10 + 16384);   GLL(Ab + 262144 + voff1, w10 + 24576);
  GLL(Bb + voff0, w10 + 32768);            GLL(Bb + voff1, w10 + 40960);
  GLL(Bb + 262144 + voff0, w10 + 49152);   GLL(Bb + 262144 + voff1, w10 + 57344);
  GLL(Bb + 128 + voff0, w10 + 98304);      GLL(Bb + 128 + voff1, w10 + 106496);
  GLL(Bb + 128 + 262144 + voff0, w10 + 114688);
  GLL(Bb + 128 + 262144 + voff1, w10 + 122880);
  asm volatile("s_waitcnt vmcnt(4)" ::: "memory"); SB();
  BAR();

  for (int t = 0; t < 16; ++t) {
    const unsigned fb = (unsigned)((t & 1) << 16);   // current buf byte offset
    const unsigned fbn = fb ^ 65536;                 // next buf
    const u8* baseA = Ab + ((t + 1) << 7);           // A(t+1), uniform
    const u8* baseB = Bb + ((t + 2) << 7);           // B(t+2), uniform
    i32x4 blo0, bhi0, blo1, bhi1, blo2, bhi2, blo3, bhi3;
    i32x4 alo0, ahi0, alo1, ahi1, nlo0, nhi0, nlo1, nhi1;
    // ---- q0: bv(8) + avA(mi0,1); stage A0(t+1); prefetch av(mi2,3)
    DSR(blo0, bR0, "0");    DSR(bhi0, bR1, "0");
    DSR(blo1, bR0, "2048"); DSR(bhi1, bR1, "2048");
    DSR(blo2, bR0, "4096"); DSR(bhi2, bR1, "4096");
    DSR(blo3, bR0, "6144"); DSR(bhi3, bR1, "6144");
    DSR(alo0, aR0, "0");    DSR(ahi0, aR1, "0");
    DSR(alo1, aR0, "2048"); DSR(ahi1, aR1, "2048");
    if (t < 15) { GLL(baseA + voff0, fbn + w10); GLL(baseA + voff1, fbn + w10 + 8192); }
    DSR(nlo0, aR0, "4096"); DSR(nhi0, aR1, "4096");
    DSR(nlo1, aR0, "6144"); DSR(nhi1, aR1, "6144");
    WAITLG(4);                       // bv + av(mi0,1) done; prefetch in flight
    i32x8 bf[4];
    bf[0] = SHUF(blo0, bhi0); bf[1] = SHUF(blo1, bhi1);
    bf[2] = SHUF(blo2, bhi2); bf[3] = SHUF(blo3, bhi3);
    MFMA_PH(0, SHUF(alo0, ahi0), SHUF(alo1, ahi1));
    // ---- q1: stage A1(t+1); prefetch av(mi4,5)
    if (t < 15) { GLL(baseA + 262144 + voff0, fbn + w10 + 16384);
                  GLL(baseA + 262144 + voff1, fbn + w10 + 24576); }
    DSR(alo0, aR0, "8192");  DSR(ahi0, aR1, "8192");
    DSR(alo1, aR0, "10240"); DSR(ahi1, aR1, "10240");
    WAITLG(4);
    MFMA_PH(1, SHUF(nlo0, nhi0), SHUF(nlo1, nhi1));
    BAR();   // mid-tile: all waves' bv consumed -> B-space(c) writable
    // ---- q2: stage B0(t+2); prefetch av(mi6,7)
    if (t < 14) { GLL(baseB + voff0, fb + w10 + 32768);
                  GLL(baseB + voff1, fb + w10 + 40960); }
    DSR(nlo0, aR0, "12288"); DSR(nhi0, aR1, "12288");
    DSR(nlo1, aR0, "14336"); DSR(nhi1, aR1, "14336");
    WAITLG(4);
    MFMA_PH(2, SHUF(alo0, ahi0), SHUF(alo1, ahi1));
    // ---- q3: stage B1(t+2); counted vmcnt; flip
    if (t < 14) { GLL(baseB + 262144 + voff0, fb + w10 + 49152);
                  GLL(baseB + 262144 + voff1, fb + w10 + 57344); }
    WAITLG(0);
    MFMA_PH(3, SHUF(nlo0, nhi0), SHUF(nlo1, nhi1));
    if (t < 14)       { asm volatile("s_waitcnt vmcnt(4)" ::: "memory"); }
    else if (t == 14) { asm volatile("s_waitcnt vmcnt(0)" ::: "memory"); }
    SB();
    BAR();   // boundary: tile t+1 fully landed, flip buffer
    aR0 ^= 65536; aR1 ^= 65536; bR0 ^= 65536; bR1 ^= 65536;
  }

  // epilogue: per-row (max, sum-exp) over this wave's 64 cols (scale /1024)
  // C/D layout: col = lane&15, row = (lane>>4)*4 + reg
  const int chunk = (bn << 2) | wn;
#pragma unroll
  for (int mi = 0; mi < 8; ++mi) {
#pragma unroll
    for (int rr = 0; rr < 4; ++rr) {
      const int row = m0 + (wm << 7) + (mi << 4) + (g4 << 2) + rr;
      float v0 = acc[mi][0][rr] * 0.0009765625f;
      float v1 = acc[mi][1][rr] * 0.0009765625f;
      float v2 = acc[mi][2][rr] * 0.0009765625f;
      float v3 = acc[mi][3][rr] * 0.0009765625f;
      float mx = fmaxf(fmaxf(v0, v1), fmaxf(v2, v3));
#pragma unroll
      for (int o = 1; o < 16; o <<= 1) mx = fmaxf(mx, __shfl_xor(mx, o, 64));
      float s = __expf(v0 - mx) + __expf(v1 - mx) + __expf(v2 - mx) + __expf(v3 - mx);
#pragma unroll
      for (int o = 1; o < 16; o <<= 1) s += __shfl_xor(s, o, 64);
      if (ln == 0) partials[(size_t)row * NCHUNK + chunk] = make_float2(mx, s);
    }
  }
#undef MFMA_PH
#undef GLL
#undef RFL
}

// ---------- kernel 5: combine partials -> lse -> logps -> loss terms ----------
__global__ void reduce_lse(const float2* __restrict__ partials,
                           const float* __restrict__ chlog,
                           const float* __restrict__ oldlp,
                           const int* __restrict__ labels,
                           const float* __restrict__ adv,
                           float* __restrict__ out, float* __restrict__ accum) {
  const int wid = threadIdx.x >> 6, l = threadIdx.x & 63;
  const int row = blockIdx.x * 4 + wid;        // 1023*4 = 4092 exactly
  float M = -INFINITY, S = 0.f;
  for (int c = l; c < NCHUNK; c += 64) {
    float2 p = partials[(size_t)row * NCHUNK + c];
    float Mn = fmaxf(M, p.x);
    S = S * __expf(M - Mn) + p.y * __expf(p.x - Mn);
    M = Mn;
  }
#pragma unroll
  for (int o = 1; o < 64; o <<= 1) {
    float Mo = __shfl_xor(M, o, 64), So = __shfl_xor(S, o, 64);
    float Mn = fmaxf(M, Mo);
    S = S * __expf(M - Mn) + So * __expf(Mo - Mn);
    M = Mn;
  }
  if (l == 0) {
    float lse = M + __logf(S);
    float ptl = chlog[row] - lse;
    out[1 + row] = ptl;
    int b = row / 1023, t = row % 1023;
    float a = adv[b];
    float ratio = __expf(ptl - oldlp[row]);
    float l1 = ratio * a;
    float l2 = fminf(fmaxf(ratio, 0.8f), 1.3f) * a;
    float mk = (float)labels[b * 1024 + t + 1];
    atomicAdd(accum + 0, -fminf(l1, l2) * mk);
    atomicAdd(accum + 1, mk);
  }
}

__global__ void finalize_k(const float* __restrict__ accum, float* __restrict__ out) {
  out[0] = accum[0] / accum[1];
}

// ---------- launch ----------
extern "C" void kernel_launch(void* const* d_in, const int* in_sizes, int n_in,
                              void* d_out, int out_size, void* d_ws, size_t ws_size,
                              hipStream_t stream) {
  const float* hs     = (const float*)d_in[0];   // (4,1024,2048)
  const float* W      = (const float*)d_in[1];   // (2048,32768)
  const int*   ids    = (const int*)d_in[2];     // (4,1024)
  const int*   labels = (const int*)d_in[3];     // (4,1024)
  const float* adv    = (const float*)d_in[4];   // (4,)
  const float* oldlp  = (const float*)d_in[5];   // (4,1023)
  float* out = (float*)d_out;                    // [loss, 4092 x per_token_logps]

  // ws layout (~92.4 MB)
  char* ws = (char*)d_ws;
  u8*     WT8      = (u8*)ws;                          //  67,108,864 B
  u8*     h8       = (u8*)(ws + 67108864);             //   8,388,608 B
  float2* partials = (float2*)(ws + 75497472);         //  16,777,216 B
  float*  chlog    = (float*)(ws + 92274688);          //      16,384 B
  int*    chosen   = (int*)(ws + 92291072);            //      16,384 B
  float*  accum    = (float*)(ws + 92307456);          //          64 B (pad)
  int*    boff     = (int*)(ws + 92307520);            //       2,112 B (513+pad)
  int*    bent     = (int*)(ws + 92309632);            //      16,384 B

  (void)hipFuncSetAttribute((const void*)gemm_lse,
                            hipFuncAttributeMaxDynamicSharedMemorySize, 131072);

  init_k<<<16, 256, 0, stream>>>(ids, chosen, chlog, accum);
  bucket_k<<<1, 512, 0, stream>>>(chosen, boff, bent);
  conv_h<<<4096, 256, 0, stream>>>(hs, h8);
  transpose_w<<<dim3(512, 32), 256, 0, stream>>>(W, WT8, hs, boff, bent, chlog);
  gemm_lse<<<2048, 512, 131072, stream>>>(h8, WT8, partials);
  reduce_lse<<<1023, 256, 0, stream>>>(partials, chlog, oldlp, labels, adv, out, accum);
  finalize_k<<<1, 1, 0, stream>>>(accum, out);
}

// Round 9
// 574.687 us; speedup vs baseline: 1.6435x; 1.0176x over previous
//
#include <hip/hip_runtime.h>
#include <hip/hip_bf16.h>

typedef unsigned short u16;
typedef unsigned char u8;
typedef unsigned long long u64;
typedef __attribute__((ext_vector_type(4))) int i32x4;
typedef __attribute__((ext_vector_type(8))) int i32x8;
typedef __attribute__((ext_vector_type(4))) float f32x4;

#define NROWS 4092      // 4 * 1023 valid token rows
#define NROWS_PAD 4096
#define DDIM 2048
#define VDIM 32768
#define NCHUNK 512      // 64-wide vocab chunks per row
#define SC8 0x7F7F7F7F  // e8m0 scale = 1.0 in all four bytes

// ---------- helpers ----------
// RNE fp32 -> OCP e4m3fn (manual, incl. denormals + saturation to 448)
__device__ __forceinline__ u8 f2fp8(float f) {
  union { float f; unsigned u; } v; v.f = f;
  unsigned s = (v.u >> 24) & 0x80u;
  unsigned a = v.u & 0x7FFFFFFFu;
  if (a >= 0x43E80000u) return (u8)(s | 0x7E);   // |f| >= 464 -> 448
  int e = (int)(a >> 23) - 127;
  unsigned m = a & 0x7FFFFFu;
  if (e < -6) {                                   // denormal target
    unsigned full = m | 0x800000u;
    int sh = 20 + (-6 - e);
    if (sh > 31) return (u8)s;
    unsigned q = full >> sh;
    unsigned rem = full & ((1u << sh) - 1u), half = 1u << (sh - 1);
    q += (rem > half || (rem == half && (q & 1u)));
    return (u8)(s | q);
  }
  unsigned q = m >> 20, rem = m & 0xFFFFFu;
  q += (rem > 0x80000u || (rem == 0x80000u && (q & 1u)));
  unsigned bits = (((unsigned)(e + 7)) << 3) + q;
  if (bits >= 0x7Fu) bits = 0x7Eu;
  return (u8)(s | bits);
}

__device__ __forceinline__ void gload16(const void* g, void* l) {
  using gp_t = const __attribute__((address_space(1))) unsigned*;
  using lp_t = __attribute__((address_space(3))) unsigned*;
  __builtin_amdgcn_global_load_lds((gp_t)g, (lp_t)(unsigned)(unsigned long long)l,
                                   16, 0, 0);
}

#define BAR() __builtin_amdgcn_s_barrier()
#define SB()  __builtin_amdgcn_sched_barrier(0)
#define SHUF(a, b) __builtin_shufflevector(a, b, 0, 1, 2, 3, 4, 5, 6, 7)

// ---------- kernel 1: chosen ids (padded) + zero chlog/accum ----------
__global__ void init_k(const int* __restrict__ ids, int* __restrict__ chosen,
                       float* __restrict__ chlog, float* __restrict__ accum) {
  int i = blockIdx.x * 256 + threadIdx.x;
  if (i < NROWS_PAD) {
    int v = -1;
    if (i < NROWS) { int b = i / 1023, t = i % 1023; v = ids[b * 1024 + t + 1]; }
    chosen[i] = v;
    chlog[i] = 0.f;
  }
  if (i < 2) accum[i] = 0.f;
}

// ---------- kernel 1b: bucket chosen ids by 64-wide vocab tile ----------
__global__ void bucket_k(const int* __restrict__ chosen,
                         int* __restrict__ boff, int* __restrict__ bent) {
  __shared__ int cnt[512];
  __shared__ int base[512];
  int tid = threadIdx.x;             // 512 threads
  cnt[tid] = 0;
  __syncthreads();
  int loc[8], tile[8];
#pragma unroll
  for (int j = 0; j < 8; ++j) {
    int r = tid + (j << 9);
    int c = chosen[r];
    int ti = (c < 0) ? 512 : (c >> 6);
    tile[j] = ti;
    loc[j] = (ti < 512) ? atomicAdd(&cnt[ti], 1) : 0;
  }
  __syncthreads();
  if (tid == 0) {
    int s = 0;
    for (int i = 0; i < 512; ++i) { base[i] = s; s += cnt[i]; }
  }
  __syncthreads();
  boff[tid] = base[tid];
  if (tid == 511) boff[512] = base[511] + cnt[511];
#pragma unroll
  for (int j = 0; j < 8; ++j) {
    int r = tid + (j << 9);
    if (tile[j] < 512) bent[base[tile[j]] + loc[j]] = (r << 6) | (chosen[r] & 63);
  }
}

// ---------- kernel 2: h fp32 -> fp8 e4m3 (x16), row-remapped, padded ------
__global__ void conv_h(const float* __restrict__ hs, u8* __restrict__ h8) {
  int idx = blockIdx.x * 256 + threadIdx.x;   // 1,048,576 threads, 8 elems each
  int row = idx >> 8;
  int c8 = (idx & 255) << 3;
  u64 o = 0;
  if (row < NROWS) {
    int b = row / 1023, t = row % 1023;
    const float* p = hs + (size_t)((b << 10) + t) * DDIM + c8;
    float4 x = *(const float4*)p, y = *(const float4*)(p + 4);
    o = (u64)f2fp8(x.x * 16.f)        | ((u64)f2fp8(x.y * 16.f) << 8) |
        ((u64)f2fp8(x.z * 16.f) << 16) | ((u64)f2fp8(x.w * 16.f) << 24) |
        ((u64)f2fp8(y.x * 16.f) << 32) | ((u64)f2fp8(y.y * 16.f) << 40) |
        ((u64)f2fp8(y.z * 16.f) << 48) | ((u64)f2fp8(y.w * 16.f) << 56);
  }
  *(u64*)(h8 + (size_t)row * DDIM + c8) = o;
}

// ---------- kernel 3: W (D x V fp32) -> W^T (V x D fp8 e4m3 x64)
//            + EXACT fp32 chosen-logit partial dots (atomicAdd into chlog) ---
__global__ void transpose_w(const float* __restrict__ W, u8* __restrict__ WT8,
                            const float* __restrict__ hs,
                            const int* __restrict__ boff,
                            const int* __restrict__ bent,
                            float* __restrict__ chlog) {
  __shared__ float t32[64][65];     // [d][v] fp32 tile (exact dots)
  __shared__ u8 t8[64][68];         // [d][v] quantized
  int v0 = blockIdx.x << 6, d0 = blockIdx.y << 6;
  int tid = threadIdx.x;
  int vi = (tid & 15) << 2, dl = tid >> 4;
#pragma unroll
  for (int i = 0; i < 4; ++i) {
    int d = dl + (i << 4);
    float4 w = *(const float4*)(W + (size_t)(d0 + d) * VDIM + v0 + vi);
    t32[d][vi + 0] = w.x; t32[d][vi + 1] = w.y;
    t32[d][vi + 2] = w.z; t32[d][vi + 3] = w.w;
    t8[d][vi + 0] = f2fp8(w.x * 64.f); t8[d][vi + 1] = f2fp8(w.y * 64.f);
    t8[d][vi + 2] = f2fp8(w.z * 64.f); t8[d][vi + 3] = f2fp8(w.w * 64.f);
  }
  __syncthreads();
  // transposed fp8 write: wave-coalesced 16B chunks
  int vr = tid >> 2, dc = (tid & 3) << 4;
  union { u8 b[16]; ulonglong2 q; } u;
#pragma unroll
  for (int k = 0; k < 16; ++k) u.b[k] = t8[dc + k][vr];
  *(ulonglong2*)(WT8 + (size_t)(v0 + vr) * DDIM + d0 + dc) = u.q;
  // exact chosen dots from the pre-bucketed list: one wave per match
  int m0 = boff[blockIdx.x], m1 = boff[blockIdx.x + 1];
  int lane = tid & 63, wv = tid >> 6;
  for (int m = m0 + wv; m < m1; m += 4) {
    int e = bent[m];
    int r = e >> 6, cv = e & 63;
    int b = r / 1023, tt = r % 1023;
    float s = hs[(size_t)((b << 10) + tt) * DDIM + d0 + lane] * t32[lane][cv];
#pragma unroll
    for (int o = 1; o < 64; o <<= 1) s += __shfl_xor(s, o, 64);
    if (lane == 0) atomicAdd(chlog + r, s);
  }
}

// ---------- kernel 4: 256x256 fp8 GEMM (mfma_scale 16x16x128) + online-LSE -
// A8: [4096][2048] fp8 (x16, zero-padded rows), Bt8: [32768][2048] fp8 (x64)
// LDS (128 KiB): [buf][A/B][half(128 rows)][128 B/row], BK=128, 16 K-tiles.
// LDS fragment reads are plain C++ loads (compiler-scheduled lgkmcnt, no asm
// copies -> no spill); staging keeps global_load_lds + counted vmcnt(4) + 2
// barriers/tile, with sched_barrier(0) pinning loads on both sides of BARs.
__global__ __launch_bounds__(512, 2) void gemm_lse(
    const u8* __restrict__ A, const u8* __restrict__ Bt,
    float2* __restrict__ partials) {
  extern __shared__ u16 smem[];
  char* lds = (char*)smem;

  const int tid = threadIdx.x;
  const int l = tid & 63;
  const int wid = tid >> 6;                // 8 waves
  const int wm = wid >> 2, wn = wid & 3;   // 2 x 4
  const int ln = l & 15;
  const int g4 = l >> 4;
  const int xr = ln & 7;

  // XCD-bijective swizzle (2048 % 8 == 0)
  int bid = blockIdx.x;
  int id = ((bid & 7) << 8) | (bid >> 3);
  int bm = id & 15;                  // 0..15
  int bn = id >> 4;                  // 0..127
  const int m0 = bm << 8, n0 = bn << 8;

  const u8* Ab = A + (size_t)m0 * DDIM;
  const u8* Bb = Bt + (size_t)n0 * DDIM;

  // swizzled LDS read offsets: slot = ((g4<<1)|u) ^ xr, 16B units
  const unsigned aA0 = (wm << 14) + (ln << 7) + ((((g4 << 1) | 0) ^ xr) << 4);
  const unsigned aA1 = (wm << 14) + (ln << 7) + ((((g4 << 1) | 1) ^ xr) << 4);
  const unsigned aB0 = 32768u + ((wn >> 1) << 14) + ((((wn & 1) << 6) | ln) << 7) + ((((g4 << 1) | 0) ^ xr) << 4);
  const unsigned aB1 = 32768u + ((wn >> 1) << 14) + ((((wn & 1) << 6) | ln) << 7) + ((((g4 << 1) | 1) ^ xr) << 4);

  // staging: lane voffsets (pre-permuted source), wave-uniform dest pieces
  const int srow = l >> 3;
  const unsigned selb = (unsigned)(((l & 7) ^ srow) << 4);   // bytes
  const unsigned voff0 = (unsigned)(((wid << 3) | srow) * 2048) + selb;       // rows 0..63
  const unsigned voff1 = (unsigned)((((8 + wid) << 3) | srow) * 2048) + selb; // rows 64..127
  const int w10 = wid << 10;

#define RFL(x) __builtin_amdgcn_readfirstlane((int)(x))
#define GLL(src, dst) gload16((src), lds + RFL(dst))
#define LD4(off) (*(const i32x4*)(lds + (off)))
#define FRAG(b0, b1, o) SHUF(LD4((b0) + (o)), LD4((b1) + (o)))

#define MFMA_PH(q, A0, A1) do {                                                \
    __builtin_amdgcn_s_setprio(1);                                             \
    _Pragma("unroll")                                                          \
    for (int _ni = 0; _ni < 4; ++_ni)                                          \
      acc[(q) * 2][_ni] = __builtin_amdgcn_mfma_scale_f32_16x16x128_f8f6f4(    \
          (A0), bf[_ni], acc[(q) * 2][_ni], 0, 0, 0, SC8, 0, SC8);             \
    _Pragma("unroll")                                                          \
    for (int _ni = 0; _ni < 4; ++_ni)                                          \
      acc[(q) * 2 + 1][_ni] = __builtin_amdgcn_mfma_scale_f32_16x16x128_f8f6f4(\
          (A1), bf[_ni], acc[(q) * 2 + 1][_ni], 0, 0, 0, SC8, 0, SC8);         \
    __builtin_amdgcn_s_setprio(0);                                             \
  } while (0)

  f32x4 acc[8][4] = {};

  // prologue: A(0),B(0) -> buf0; B(1) -> buf1; wait tile0, leave B(1) in flight
  GLL(Ab + voff0, w10);                    GLL(Ab + voff1, w10 + 8192);
  GLL(Ab + 262144 + voff0, w10 + 16384);   GLL(Ab + 262144 + voff1, w10 + 24576);
  GLL(Bb + voff0, w10 + 32768);            GLL(Bb + voff1, w10 + 40960);
  GLL(Bb + 262144 + voff0, w10 + 49152);   GLL(Bb + 262144 + voff1, w10 + 57344);
  GLL(Bb + 128 + voff0, w10 + 98304);      GLL(Bb + 128 + voff1, w10 + 106496);
  GLL(Bb + 128 + 262144 + voff0, w10 + 114688);
  GLL(Bb + 128 + 262144 + voff1, w10 + 122880);
  asm volatile("s_waitcnt vmcnt(4)" ::: "memory"); SB();
  BAR();
  SB();

  for (int t = 0; t < 16; ++t) {
    const unsigned fb = (unsigned)((t & 1) << 16);   // current buf byte offset
    const unsigned fbn = fb ^ 65536u;                // next buf
    const u8* baseA = Ab + ((t + 1) << 7);           // A(t+1), uniform
    const u8* baseB = Bb + ((t + 2) << 7);           // B(t+2), uniform
    const unsigned rA0 = fb + aA0, rA1 = fb + aA1;
    const unsigned rB0 = fb + aB0, rB1 = fb + aB1;

    // B operands for the whole tile (8 ds_read_b128 -> 4 x i32x8)
    i32x8 bf[4];
#pragma unroll
    for (int ni = 0; ni < 4; ++ni) bf[ni] = FRAG(rB0, rB1, ni * 2048);

    // ---- q0: A rows 0..31; stage A0(t+1)
    i32x8 a0 = FRAG(rA0, rA1, 0), a1 = FRAG(rA0, rA1, 2048);
    if (t < 15) { GLL(baseA + voff0, fbn + w10); GLL(baseA + voff1, fbn + w10 + 8192); }
    MFMA_PH(0, a0, a1);
    // ---- q1: A rows 32..63; stage A1(t+1)
    a0 = FRAG(rA0, rA1, 4096); a1 = FRAG(rA0, rA1, 6144);
    if (t < 15) { GLL(baseA + 262144 + voff0, fbn + w10 + 16384);
                  GLL(baseA + 262144 + voff1, fbn + w10 + 24576); }
    MFMA_PH(1, a0, a1);
    SB();
    BAR();   // mid-tile: all waves' bv consumed -> B-space(fb) writable
    // ---- q2: A rows 64..95; stage B0(t+2) into current buf's B-space
    a0 = FRAG(rA0, rA1, 8192); a1 = FRAG(rA0, rA1, 10240);
    if (t < 14) { GLL(baseB + voff0, fb + w10 + 32768);
                  GLL(baseB + voff1, fb + w10 + 40960); }
    MFMA_PH(2, a0, a1);
    // ---- q3: A rows 96..127; stage B1(t+2); counted vmcnt; flip
    a0 = FRAG(rA0, rA1, 12288); a1 = FRAG(rA0, rA1, 14336);
    if (t < 14) { GLL(baseB + 262144 + voff0, fb + w10 + 49152);
                  GLL(baseB + 262144 + voff1, fb + w10 + 57344); }
    MFMA_PH(3, a0, a1);
    if (t < 14)       { asm volatile("s_waitcnt vmcnt(4)" ::: "memory"); }
    else if (t == 14) { asm volatile("s_waitcnt vmcnt(0)" ::: "memory"); }
    SB();
    BAR();   // boundary: tile t+1 fully landed, flip buffer
    SB();
  }

  // epilogue: per-row (max, sum-exp) over this wave's 64 cols (scale /1024)
  // C/D layout: col = lane&15, row = (lane>>4)*4 + reg
  const int chunk = (bn << 2) | wn;
#pragma unroll
  for (int mi = 0; mi < 8; ++mi) {
#pragma unroll
    for (int rr = 0; rr < 4; ++rr) {
      const int row = m0 + (wm << 7) + (mi << 4) + (g4 << 2) + rr;
      float v0 = acc[mi][0][rr] * 0.0009765625f;
      float v1 = acc[mi][1][rr] * 0.0009765625f;
      float v2 = acc[mi][2][rr] * 0.0009765625f;
      float v3 = acc[mi][3][rr] * 0.0009765625f;
      float mx = fmaxf(fmaxf(v0, v1), fmaxf(v2, v3));
#pragma unroll
      for (int o = 1; o < 16; o <<= 1) mx = fmaxf(mx, __shfl_xor(mx, o, 64));
      float s = __expf(v0 - mx) + __expf(v1 - mx) + __expf(v2 - mx) + __expf(v3 - mx);
#pragma unroll
      for (int o = 1; o < 16; o <<= 1) s += __shfl_xor(s, o, 64);
      if (ln == 0) partials[(size_t)row * NCHUNK + chunk] = make_float2(mx, s);
    }
  }
#undef MFMA_PH
#undef FRAG
#undef LD4
#undef GLL
#undef RFL
}

// ---------- kernel 5: combine partials -> lse -> logps -> loss terms ----------
__global__ void reduce_lse(const float2* __restrict__ partials,
                           const float* __restrict__ chlog,
                           const float* __restrict__ oldlp,
                           const int* __restrict__ labels,
                           const float* __restrict__ adv,
                           float* __restrict__ out, float* __restrict__ accum) {
  const int wid = threadIdx.x >> 6, l = threadIdx.x & 63;
  const int row = blockIdx.x * 4 + wid;        // 1023*4 = 4092 exactly
  float M = -INFINITY, S = 0.f;
  for (int c = l; c < NCHUNK; c += 64) {
    float2 p = partials[(size_t)row * NCHUNK + c];
    float Mn = fmaxf(M, p.x);
    S = S * __expf(M - Mn) + p.y * __expf(p.x - Mn);
    M = Mn;
  }
#pragma unroll
  for (int o = 1; o < 64; o <<= 1) {
    float Mo = __shfl_xor(M, o, 64), So = __shfl_xor(S, o, 64);
    float Mn = fmaxf(M, Mo);
    S = S * __expf(M - Mn) + So * __expf(Mo - Mn);
    M = Mn;
  }
  if (l == 0) {
    float lse = M + __logf(S);
    float ptl = chlog[row] - lse;
    out[1 + row] = ptl;
    int b = row / 1023, t = row % 1023;
    float a = adv[b];
    float ratio = __expf(ptl - oldlp[row]);
    float l1 = ratio * a;
    float l2 = fminf(fmaxf(ratio, 0.8f), 1.3f) * a;
    float mk = (float)labels[b * 1024 + t + 1];
    atomicAdd(accum + 0, -fminf(l1, l2) * mk);
    atomicAdd(accum + 1, mk);
  }
}

__global__ void finalize_k(const float* __restrict__ accum, float* __restrict__ out) {
  out[0] = accum[0] / accum[1];
}

// ---------- launch ----------
extern "C" void kernel_launch(void* const* d_in, const int* in_sizes, int n_in,
                              void* d_out, int out_size, void* d_ws, size_t ws_size,
                              hipStream_t stream) {
  const float* hs     = (const float*)d_in[0];   // (4,1024,2048)
  const float* W      = (const float*)d_in[1];   // (2048,32768)
  const int*   ids    = (const int*)d_in[2];     // (4,1024)
  const int*   labels = (const int*)d_in[3];     // (4,1024)
  const float* adv    = (const float*)d_in[4];   // (4,)
  const float* oldlp  = (const float*)d_in[5];   // (4,1023)
  float* out = (float*)d_out;                    // [loss, 4092 x per_token_logps]

  // ws layout (~92.4 MB)
  char* ws = (char*)d_ws;
  u8*     WT8      = (u8*)ws;                          //  67,108,864 B
  u8*     h8       = (u8*)(ws + 67108864);             //   8,388,608 B
  float2* partials = (float2*)(ws + 75497472);         //  16,777,216 B
  float*  chlog    = (float*)(ws + 92274688);          //      16,384 B
  int*    chosen   = (int*)(ws + 92291072);            //      16,384 B
  float*  accum    = (float*)(ws + 92307456);          //          64 B (pad)
  int*    boff     = (int*)(ws + 92307520);            //       2,112 B (513+pad)
  int*    bent     = (int*)(ws + 92309632);            //      16,384 B

  (void)hipFuncSetAttribute((const void*)gemm_lse,
                            hipFuncAttributeMaxDynamicSharedMemorySize, 131072);

  init_k<<<16, 256, 0, stream>>>(ids, chosen, chlog, accum);
  bucket_k<<<1, 512, 0, stream>>>(chosen, boff, bent);
  conv_h<<<4096, 256, 0, stream>>>(hs, h8);
  transpose_w<<<dim3(512, 32), 256, 0, stream>>>(W, WT8, hs, boff, bent, chlog);
  gemm_lse<<<2048, 512, 131072, stream>>>(h8, WT8, partials);
  reduce_lse<<<1023, 256, 0, stream>>>(partials, chlog, oldlp, labels, adv, out, accum);
  finalize_k<<<1, 1, 0, stream>>>(accum, out);
}

// Round 10
// 564.665 us; speedup vs baseline: 1.6727x; 1.0177x over previous
//
#include <hip/hip_runtime.h>
#include <hip/hip_bf16.h>

typedef unsigned short u16;
typedef unsigned char u8;
typedef unsigned long long u64;
typedef __attribute__((ext_vector_type(4))) int i32x4;
typedef __attribute__((ext_vector_type(8))) int i32x8;
typedef __attribute__((ext_vector_type(4))) float f32x4;

#define NROWS 4092      // 4 * 1023 valid token rows
#define NROWS_PAD 4096
#define DDIM 2048
#define VDIM 32768
#define NCHUNK 512      // 64-wide vocab chunks per row
#define SC8 0x7F7F7F7F  // e8m0 scale = 1.0 in all four bytes
#define BUFB 49152u     // LDS bytes per buffer: A 16K + B 32K

// ---------- helpers ----------
// RNE fp32 -> OCP e4m3fn (manual, incl. denormals + saturation to 448)
__device__ __forceinline__ u8 f2fp8(float f) {
  union { float f; unsigned u; } v; v.f = f;
  unsigned s = (v.u >> 24) & 0x80u;
  unsigned a = v.u & 0x7FFFFFFFu;
  if (a >= 0x43E80000u) return (u8)(s | 0x7E);   // |f| >= 464 -> 448
  int e = (int)(a >> 23) - 127;
  unsigned m = a & 0x7FFFFFu;
  if (e < -6) {                                   // denormal target
    unsigned full = m | 0x800000u;
    int sh = 20 + (-6 - e);
    if (sh > 31) return (u8)s;
    unsigned q = full >> sh;
    unsigned rem = full & ((1u << sh) - 1u), half = 1u << (sh - 1);
    q += (rem > half || (rem == half && (q & 1u)));
    return (u8)(s | q);
  }
  unsigned q = m >> 20, rem = m & 0xFFFFFu;
  q += (rem > 0x80000u || (rem == 0x80000u && (q & 1u)));
  unsigned bits = (((unsigned)(e + 7)) << 3) + q;
  if (bits >= 0x7Fu) bits = 0x7Eu;
  return (u8)(s | bits);
}

__device__ __forceinline__ void gload16(const void* g, void* l) {
  using gp_t = const __attribute__((address_space(1))) unsigned*;
  using lp_t = __attribute__((address_space(3))) unsigned*;
  __builtin_amdgcn_global_load_lds((gp_t)g, (lp_t)(unsigned)(unsigned long long)l,
                                   16, 0, 0);
}

#define BAR() __builtin_amdgcn_s_barrier()
#define SB()  __builtin_amdgcn_sched_barrier(0)
#define SHUF(a, b) __builtin_shufflevector(a, b, 0, 1, 2, 3, 4, 5, 6, 7)

// ---------- kernel 1: chosen ids (padded) + zero chlog/accum ----------
__global__ void init_k(const int* __restrict__ ids, int* __restrict__ chosen,
                       float* __restrict__ chlog, float* __restrict__ accum) {
  int i = blockIdx.x * 256 + threadIdx.x;
  if (i < NROWS_PAD) {
    int v = -1;
    if (i < NROWS) { int b = i / 1023, t = i % 1023; v = ids[b * 1024 + t + 1]; }
    chosen[i] = v;
    chlog[i] = 0.f;
  }
  if (i < 2) accum[i] = 0.f;
}

// ---------- kernel 1b: bucket chosen ids by 64-wide vocab tile ----------
__global__ void bucket_k(const int* __restrict__ chosen,
                         int* __restrict__ boff, int* __restrict__ bent) {
  __shared__ int cnt[512];
  __shared__ int base[512];
  int tid = threadIdx.x;             // 512 threads
  cnt[tid] = 0;
  __syncthreads();
  int loc[8], tile[8];
#pragma unroll
  for (int j = 0; j < 8; ++j) {
    int r = tid + (j << 9);
    int c = chosen[r];
    int ti = (c < 0) ? 512 : (c >> 6);
    tile[j] = ti;
    loc[j] = (ti < 512) ? atomicAdd(&cnt[ti], 1) : 0;
  }
  __syncthreads();
  if (tid == 0) {
    int s = 0;
    for (int i = 0; i < 512; ++i) { base[i] = s; s += cnt[i]; }
  }
  __syncthreads();
  boff[tid] = base[tid];
  if (tid == 511) boff[512] = base[511] + cnt[511];
#pragma unroll
  for (int j = 0; j < 8; ++j) {
    int r = tid + (j << 9);
    if (tile[j] < 512) bent[base[tile[j]] + loc[j]] = (r << 6) | (chosen[r] & 63);
  }
}

// ---------- kernel 2: h fp32 -> fp8 e4m3 (x16), row-remapped, padded ------
__global__ void conv_h(const float* __restrict__ hs, u8* __restrict__ h8) {
  int idx = blockIdx.x * 256 + threadIdx.x;   // 1,048,576 threads, 8 elems each
  int row = idx >> 8;
  int c8 = (idx & 255) << 3;
  u64 o = 0;
  if (row < NROWS) {
    int b = row / 1023, t = row % 1023;
    const float* p = hs + (size_t)((b << 10) + t) * DDIM + c8;
    float4 x = *(const float4*)p, y = *(const float4*)(p + 4);
    o = (u64)f2fp8(x.x * 16.f)        | ((u64)f2fp8(x.y * 16.f) << 8) |
        ((u64)f2fp8(x.z * 16.f) << 16) | ((u64)f2fp8(x.w * 16.f) << 24) |
        ((u64)f2fp8(y.x * 16.f) << 32) | ((u64)f2fp8(y.y * 16.f) << 40) |
        ((u64)f2fp8(y.z * 16.f) << 48) | ((u64)f2fp8(y.w * 16.f) << 56);
  }
  *(u64*)(h8 + (size_t)row * DDIM + c8) = o;
}

// ---------- kernel 3: W (D x V fp32) -> W^T (V x D fp8 e4m3 x64)
//            + EXACT fp32 chosen-logit partial dots (atomicAdd into chlog) ---
__global__ void transpose_w(const float* __restrict__ W, u8* __restrict__ WT8,
                            const float* __restrict__ hs,
                            const int* __restrict__ boff,
                            const int* __restrict__ bent,
                            float* __restrict__ chlog) {
  __shared__ float t32[64][65];     // [d][v] fp32 tile (exact dots)
  __shared__ u8 t8[64][68];         // [d][v] quantized
  int v0 = blockIdx.x << 6, d0 = blockIdx.y << 6;
  int tid = threadIdx.x;
  int vi = (tid & 15) << 2, dl = tid >> 4;
#pragma unroll
  for (int i = 0; i < 4; ++i) {
    int d = dl + (i << 4);
    float4 w = *(const float4*)(W + (size_t)(d0 + d) * VDIM + v0 + vi);
    t32[d][vi + 0] = w.x; t32[d][vi + 1] = w.y;
    t32[d][vi + 2] = w.z; t32[d][vi + 3] = w.w;
    t8[d][vi + 0] = f2fp8(w.x * 64.f); t8[d][vi + 1] = f2fp8(w.y * 64.f);
    t8[d][vi + 2] = f2fp8(w.z * 64.f); t8[d][vi + 3] = f2fp8(w.w * 64.f);
  }
  __syncthreads();
  // transposed fp8 write: wave-coalesced 16B chunks
  int vr = tid >> 2, dc = (tid & 3) << 4;
  union { u8 b[16]; ulonglong2 q; } u;
#pragma unroll
  for (int k = 0; k < 16; ++k) u.b[k] = t8[dc + k][vr];
  *(ulonglong2*)(WT8 + (size_t)(v0 + vr) * DDIM + d0 + dc) = u.q;
  // exact chosen dots from the pre-bucketed list: one wave per match
  int m0 = boff[blockIdx.x], m1 = boff[blockIdx.x + 1];
  int lane = tid & 63, wv = tid >> 6;
  for (int m = m0 + wv; m < m1; m += 4) {
    int e = bent[m];
    int r = e >> 6, cv = e & 63;
    int b = r / 1023, tt = r % 1023;
    float s = hs[(size_t)((b << 10) + tt) * DDIM + d0 + lane] * t32[lane][cv];
#pragma unroll
    for (int o = 1; o < 64; o <<= 1) s += __shfl_xor(s, o, 64);
    if (lane == 0) atomicAdd(chlog + r, s);
  }
}

// ---------- kernel 4: 128x256 fp8 GEMM (mfma_scale 16x16x128) + online-LSE -
// A8: [4096][2048] fp8 (x16, zero-padded rows), Bt8: [32768][2048] fp8 (x64)
// 8 waves (2x4), wave tile 64x64 -> acc[4][4] = 64 AGPRs (spill-proof).
// LDS 96 KiB: [buf(49152)][A 16K | B 32K], rows of 128 B, XOR-swizzled reads
// with pre-permuted global sources. 16 K-tiles of BK=128; counted vmcnt(4)
// at boundary (B(t+2)'s 4 loads stay in flight); 2 barriers/tile.
__global__ __launch_bounds__(512, 2) void gemm_lse(
    const u8* __restrict__ A, const u8* __restrict__ Bt,
    float2* __restrict__ partials) {
  extern __shared__ u16 smem[];
  char* lds = (char*)smem;

  const int tid = threadIdx.x;
  const int l = tid & 63;
  const int wid = tid >> 6;                // 8 waves
  const int wmr = wid >> 2, wnr = wid & 3; // 2 x 4
  const int ln = l & 15;
  const int g4 = l >> 4;
  const int xr = ln & 7;

  // XCD-bijective swizzle (4096 % 8 == 0): each XCD owns 16 bn panels
  int bid = blockIdx.x;
  int id = ((bid & 7) << 9) | (bid >> 3);
  int bm = id & 31;                  // 0..31 (M tiles of 128)
  int bn = id >> 5;                  // 0..127 (N tiles of 256)
  const int m0 = bm << 7, n0 = bn << 8;

  const u8* Ab = A + (size_t)m0 * DDIM;
  const u8* Bb = Bt + (size_t)n0 * DDIM;

  // swizzled LDS read offsets: slot = ((g4<<1)|u) ^ xr, 16B units
  const unsigned aA0 = (unsigned)(((wmr << 6) | ln) << 7) + ((((g4 << 1) | 0) ^ xr) << 4);
  const unsigned aA1 = (unsigned)(((wmr << 6) | ln) << 7) + ((((g4 << 1) | 1) ^ xr) << 4);
  const unsigned aB0 = 16384u + (unsigned)(((wnr << 6) | ln) << 7) + ((((g4 << 1) | 0) ^ xr) << 4);
  const unsigned aB1 = 16384u + (unsigned)(((wnr << 6) | ln) << 7) + ((((g4 << 1) | 1) ^ xr) << 4);

  // staging: lane voffsets (pre-permuted source), wave-uniform dest pieces
  const int srow = l >> 3;
  const unsigned selb = (unsigned)(((l & 7) ^ srow) << 4);   // bytes
  const unsigned voff0 = (unsigned)((((0  + wid) << 3) | srow) * 2048) + selb; // rows 0..63
  const unsigned voff1 = (unsigned)((((8  + wid) << 3) | srow) * 2048) + selb; // rows 64..127
  const unsigned voff2 = (unsigned)((((16 + wid) << 3) | srow) * 2048) + selb; // rows 128..191
  const unsigned voff3 = (unsigned)((((24 + wid) << 3) | srow) * 2048) + selb; // rows 192..255
  const int w10 = wid << 10;

#define RFL(x) __builtin_amdgcn_readfirstlane((int)(x))
#define GLL(src, dst) gload16((src), lds + RFL(dst))
#define LD4(off) (*(const i32x4*)(lds + (off)))
#define FRAG(b0, b1, o) SHUF(LD4((b0) + (o)), LD4((b1) + (o)))

#define MFMA4(q, af) do {                                                      \
    __builtin_amdgcn_s_setprio(1);                                             \
    _Pragma("unroll")                                                          \
    for (int _ni = 0; _ni < 4; ++_ni)                                          \
      acc[(q)][_ni] = __builtin_amdgcn_mfma_scale_f32_16x16x128_f8f6f4(        \
          (af), bf[_ni], acc[(q)][_ni], 0, 0, 0, SC8, 0, SC8);                 \
    __builtin_amdgcn_s_setprio(0);                                             \
  } while (0)

  f32x4 acc[4][4] = {};

  // prologue: A(0),B(0) -> buf0; B(1) -> buf1; wait tile0, leave B(1) in flight
  GLL(Ab + voff0, w10);                 GLL(Ab + voff1, 8192 + w10);
  GLL(Bb + voff0, 16384 + w10);         GLL(Bb + voff1, 24576 + w10);
  GLL(Bb + voff2, 32768 + w10);         GLL(Bb + voff3, 40960 + w10);
  GLL(Bb + 128 + voff0, BUFB + 16384 + w10);
  GLL(Bb + 128 + voff1, BUFB + 24576 + w10);
  GLL(Bb + 128 + voff2, BUFB + 32768 + w10);
  GLL(Bb + 128 + voff3, BUFB + 40960 + w10);
  asm volatile("s_waitcnt vmcnt(4)" ::: "memory"); SB();
  BAR();
  SB();

  for (int t = 0; t < 16; ++t) {
    const unsigned fb = (unsigned)(t & 1) * BUFB;    // current buf byte offset
    const unsigned fbn = BUFB - fb;                  // next buf
    const u8* baseA = Ab + ((t + 1) << 7);           // A(t+1), uniform
    const u8* baseB = Bb + ((t + 2) << 7);           // B(t+2), uniform
    const unsigned rA0 = fb + aA0, rA1 = fb + aA1;
    const unsigned rB0 = fb + aB0, rB1 = fb + aB1;

    // B operands for the whole tile (8 ds_read_b128 -> 4 x i32x8)
    i32x8 bf[4];
#pragma unroll
    for (int ni = 0; ni < 4; ++ni) bf[ni] = FRAG(rB0, rB1, ni * 2048);

    // ---- q0: A rows 0..15; stage A(t+1) half0
    i32x8 af = FRAG(rA0, rA1, 0);
    if (t < 15) GLL(baseA + voff0, fbn + w10);
    MFMA4(0, af);
    // ---- q1: A rows 16..31; stage A(t+1) half1
    af = FRAG(rA0, rA1, 2048);
    if (t < 15) GLL(baseA + voff1, fbn + 8192 + w10);
    MFMA4(1, af);
    SB();
    BAR();   // mid-tile: all waves' bf consumed -> B-space(fb) writable
    SB();
    // ---- q2: A rows 32..47; stage B(t+2) rows 0..127
    af = FRAG(rA0, rA1, 4096);
    if (t < 14) { GLL(baseB + voff0, fb + 16384 + w10);
                  GLL(baseB + voff1, fb + 24576 + w10); }
    MFMA4(2, af);
    // ---- q3: A rows 48..63; stage B(t+2) rows 128..255; counted vmcnt; flip
    af = FRAG(rA0, rA1, 6144);
    if (t < 14) { GLL(baseB + voff2, fb + 32768 + w10);
                  GLL(baseB + voff3, fb + 40960 + w10); }
    MFMA4(3, af);
    if (t < 14)       { asm volatile("s_waitcnt vmcnt(4)" ::: "memory"); }
    else if (t == 14) { asm volatile("s_waitcnt vmcnt(0)" ::: "memory"); }
    SB();
    BAR();   // boundary: tile t+1 fully landed, flip buffer
    SB();
  }

  // epilogue: per-row (max, sum-exp) over this wave's 64 cols (scale /1024)
  // C/D layout: col = lane&15, row = (lane>>4)*4 + reg
  const int chunk = (bn << 2) | wnr;
#pragma unroll
  for (int mi = 0; mi < 4; ++mi) {
#pragma unroll
    for (int rr = 0; rr < 4; ++rr) {
      const int row = m0 + (wmr << 6) + (mi << 4) + (g4 << 2) + rr;
      float v0 = acc[mi][0][rr] * 0.0009765625f;
      float v1 = acc[mi][1][rr] * 0.0009765625f;
      float v2 = acc[mi][2][rr] * 0.0009765625f;
      float v3 = acc[mi][3][rr] * 0.0009765625f;
      float mx = fmaxf(fmaxf(v0, v1), fmaxf(v2, v3));
#pragma unroll
      for (int o = 1; o < 16; o <<= 1) mx = fmaxf(mx, __shfl_xor(mx, o, 64));
      float s = __expf(v0 - mx) + __expf(v1 - mx) + __expf(v2 - mx) + __expf(v3 - mx);
#pragma unroll
      for (int o = 1; o < 16; o <<= 1) s += __shfl_xor(s, o, 64);
      if (ln == 0) partials[(size_t)row * NCHUNK + chunk] = make_float2(mx, s);
    }
  }
#undef MFMA4
#undef FRAG
#undef LD4
#undef GLL
#undef RFL
}

// ---------- kernel 5: combine partials -> lse -> logps -> loss terms ----------
__global__ void reduce_lse(const float2* __restrict__ partials,
                           const float* __restrict__ chlog,
                           const float* __restrict__ oldlp,
                           const int* __restrict__ labels,
                           const float* __restrict__ adv,
                           float* __restrict__ out, float* __restrict__ accum) {
  const int wid = threadIdx.x >> 6, l = threadIdx.x & 63;
  const int row = blockIdx.x * 4 + wid;        // 1023*4 = 4092 exactly
  float M = -INFINITY, S = 0.f;
  for (int c = l; c < NCHUNK; c += 64) {
    float2 p = partials[(size_t)row * NCHUNK + c];
    float Mn = fmaxf(M, p.x);
    S = S * __expf(M - Mn) + p.y * __expf(p.x - Mn);
    M = Mn;
  }
#pragma unroll
  for (int o = 1; o < 64; o <<= 1) {
    float Mo = __shfl_xor(M, o, 64), So = __shfl_xor(S, o, 64);
    float Mn = fmaxf(M, Mo);
    S = S * __expf(M - Mn) + So * __expf(Mo - Mn);
    M = Mn;
  }
  if (l == 0) {
    float lse = M + __logf(S);
    float ptl = chlog[row] - lse;
    out[1 + row] = ptl;
    int b = row / 1023, t = row % 1023;
    float a = adv[b];
    float ratio = __expf(ptl - oldlp[row]);
    float l1 = ratio * a;
    float l2 = fminf(fmaxf(ratio, 0.8f), 1.3f) * a;
    float mk = (float)labels[b * 1024 + t + 1];
    atomicAdd(accum + 0, -fminf(l1, l2) * mk);
    atomicAdd(accum + 1, mk);
  }
}

__global__ void finalize_k(const float* __restrict__ accum, float* __restrict__ out) {
  out[0] = accum[0] / accum[1];
}

// ---------- launch ----------
extern "C" void kernel_launch(void* const* d_in, const int* in_sizes, int n_in,
                              void* d_out, int out_size, void* d_ws, size_t ws_size,
                              hipStream_t stream) {
  const float* hs     = (const float*)d_in[0];   // (4,1024,2048)
  const float* W      = (const float*)d_in[1];   // (2048,32768)
  const int*   ids    = (const int*)d_in[2];     // (4,1024)
  const int*   labels = (const int*)d_in[3];     // (4,1024)
  const float* adv    = (const float*)d_in[4];   // (4,)
  const float* oldlp  = (const float*)d_in[5];   // (4,1023)
  float* out = (float*)d_out;                    // [loss, 4092 x per_token_logps]

  // ws layout (~92.4 MB)
  char* ws = (char*)d_ws;
  u8*     WT8      = (u8*)ws;                          //  67,108,864 B
  u8*     h8       = (u8*)(ws + 67108864);             //   8,388,608 B
  float2* partials = (float2*)(ws + 75497472);         //  16,777,216 B
  float*  chlog    = (float*)(ws + 92274688);          //      16,384 B
  int*    chosen   = (int*)(ws + 92291072);            //      16,384 B
  float*  accum    = (float*)(ws + 92307456);          //          64 B (pad)
  int*    boff     = (int*)(ws + 92307520);            //       2,112 B (513+pad)
  int*    bent     = (int*)(ws + 92309632);            //      16,384 B

  (void)hipFuncSetAttribute((const void*)gemm_lse,
                            hipFuncAttributeMaxDynamicSharedMemorySize, 98304);

  init_k<<<16, 256, 0, stream>>>(ids, chosen, chlog, accum);
  bucket_k<<<1, 512, 0, stream>>>(chosen, boff, bent);
  conv_h<<<4096, 256, 0, stream>>>(hs, h8);
  transpose_w<<<dim3(512, 32), 256, 0, stream>>>(W, WT8, hs, boff, bent, chlog);
  gemm_lse<<<4096, 512, 98304, stream>>>(h8, WT8, partials);
  reduce_lse<<<1023, 256, 0, stream>>>(partials, chlog, oldlp, labels, adv, out, accum);
  finalize_k<<<1, 1, 0, stream>>>(accum, out);
}

// Round 11
// 548.735 us; speedup vs baseline: 1.7212x; 1.0290x over previous
//
#include <hip/hip_runtime.h>
#include <hip/hip_bf16.h>

typedef unsigned short u16;
typedef unsigned char u8;
typedef unsigned long long u64;
typedef __attribute__((ext_vector_type(4))) int i32x4;
typedef __attribute__((ext_vector_type(8))) int i32x8;
typedef __attribute__((ext_vector_type(4))) float f32x4;

#define NROWS 4092      // 4 * 1023 valid token rows
#define NROWS_PAD 4096
#define DDIM 2048
#define VDIM 32768
#define NCHUNK 512      // 64-wide vocab chunks per row
#define SC8 0x7F7F7F7F  // e8m0 scale = 1.0 in all four bytes
#define BUFB 49152u     // LDS bytes per buffer: A 16K + B 32K

// ---------- helpers ----------
// RNE fp32 -> OCP e4m3fn (manual, incl. denormals + saturation to 448)
__device__ __forceinline__ u8 f2fp8(float f) {
  union { float f; unsigned u; } v; v.f = f;
  unsigned s = (v.u >> 24) & 0x80u;
  unsigned a = v.u & 0x7FFFFFFFu;
  if (a >= 0x43E80000u) return (u8)(s | 0x7E);   // |f| >= 464 -> 448
  int e = (int)(a >> 23) - 127;
  unsigned m = a & 0x7FFFFFu;
  if (e < -6) {                                   // denormal target
    unsigned full = m | 0x800000u;
    int sh = 20 + (-6 - e);
    if (sh > 31) return (u8)s;
    unsigned q = full >> sh;
    unsigned rem = full & ((1u << sh) - 1u), half = 1u << (sh - 1);
    q += (rem > half || (rem == half && (q & 1u)));
    return (u8)(s | q);
  }
  unsigned q = m >> 20, rem = m & 0xFFFFFu;
  q += (rem > 0x80000u || (rem == 0x80000u && (q & 1u)));
  unsigned bits = (((unsigned)(e + 7)) << 3) + q;
  if (bits >= 0x7Fu) bits = 0x7Eu;
  return (u8)(s | bits);
}

__device__ __forceinline__ void gload16(const void* g, void* l) {
  using gp_t = const __attribute__((address_space(1))) unsigned*;
  using lp_t = __attribute__((address_space(3))) unsigned*;
  __builtin_amdgcn_global_load_lds((gp_t)g, (lp_t)(unsigned)(unsigned long long)l,
                                   16, 0, 0);
}

#define BAR() __builtin_amdgcn_s_barrier()
#define SB()  __builtin_amdgcn_sched_barrier(0)
#define SHUF(a, b) __builtin_shufflevector(a, b, 0, 1, 2, 3, 4, 5, 6, 7)

// ---------- kernel 1: chosen ids (padded) + zero chlog/accum ----------
__global__ void init_k(const int* __restrict__ ids, int* __restrict__ chosen,
                       float* __restrict__ chlog, float* __restrict__ accum) {
  int i = blockIdx.x * 256 + threadIdx.x;
  if (i < NROWS_PAD) {
    int v = -1;
    if (i < NROWS) { int b = i / 1023, t = i % 1023; v = ids[b * 1024 + t + 1]; }
    chosen[i] = v;
    chlog[i] = 0.f;
  }
  if (i < 2) accum[i] = 0.f;
}

// ---------- kernel 1b: bucket chosen ids by 64-wide vocab tile ----------
__global__ void bucket_k(const int* __restrict__ chosen,
                         int* __restrict__ boff, int* __restrict__ bent) {
  __shared__ int cnt[512];
  __shared__ int base[512];
  int tid = threadIdx.x;             // 512 threads
  cnt[tid] = 0;
  __syncthreads();
  int loc[8], tile[8];
#pragma unroll
  for (int j = 0; j < 8; ++j) {
    int r = tid + (j << 9);
    int c = chosen[r];
    int ti = (c < 0) ? 512 : (c >> 6);
    tile[j] = ti;
    loc[j] = (ti < 512) ? atomicAdd(&cnt[ti], 1) : 0;
  }
  __syncthreads();
  if (tid == 0) {
    int s = 0;
    for (int i = 0; i < 512; ++i) { base[i] = s; s += cnt[i]; }
  }
  __syncthreads();
  boff[tid] = base[tid];
  if (tid == 511) boff[512] = base[511] + cnt[511];
#pragma unroll
  for (int j = 0; j < 8; ++j) {
    int r = tid + (j << 9);
    if (tile[j] < 512) bent[base[tile[j]] + loc[j]] = (r << 6) | (chosen[r] & 63);
  }
}

// ---------- kernel 2: h fp32 -> fp8 e4m3 (x16), row-remapped, padded ------
__global__ void conv_h(const float* __restrict__ hs, u8* __restrict__ h8) {
  int idx = blockIdx.x * 256 + threadIdx.x;   // 1,048,576 threads, 8 elems each
  int row = idx >> 8;
  int c8 = (idx & 255) << 3;
  u64 o = 0;
  if (row < NROWS) {
    int b = row / 1023, t = row % 1023;
    const float* p = hs + (size_t)((b << 10) + t) * DDIM + c8;
    float4 x = *(const float4*)p, y = *(const float4*)(p + 4);
    o = (u64)f2fp8(x.x * 16.f)        | ((u64)f2fp8(x.y * 16.f) << 8) |
        ((u64)f2fp8(x.z * 16.f) << 16) | ((u64)f2fp8(x.w * 16.f) << 24) |
        ((u64)f2fp8(y.x * 16.f) << 32) | ((u64)f2fp8(y.y * 16.f) << 40) |
        ((u64)f2fp8(y.z * 16.f) << 48) | ((u64)f2fp8(y.w * 16.f) << 56);
  }
  *(u64*)(h8 + (size_t)row * DDIM + c8) = o;
}

// ---------- kernel 3: W (D x V fp32) -> W^T (V x D fp8 e4m3 x64)
//            + EXACT fp32 chosen-logit partial dots (atomicAdd into chlog) ---
__global__ void transpose_w(const float* __restrict__ W, u8* __restrict__ WT8,
                            const float* __restrict__ hs,
                            const int* __restrict__ boff,
                            const int* __restrict__ bent,
                            float* __restrict__ chlog) {
  __shared__ float t32[64][65];     // [d][v] fp32 tile (exact dots)
  __shared__ u8 t8[64][68];         // [d][v] quantized
  int v0 = blockIdx.x << 6, d0 = blockIdx.y << 6;
  int tid = threadIdx.x;
  int vi = (tid & 15) << 2, dl = tid >> 4;
#pragma unroll
  for (int i = 0; i < 4; ++i) {
    int d = dl + (i << 4);
    float4 w = *(const float4*)(W + (size_t)(d0 + d) * VDIM + v0 + vi);
    t32[d][vi + 0] = w.x; t32[d][vi + 1] = w.y;
    t32[d][vi + 2] = w.z; t32[d][vi + 3] = w.w;
    t8[d][vi + 0] = f2fp8(w.x * 64.f); t8[d][vi + 1] = f2fp8(w.y * 64.f);
    t8[d][vi + 2] = f2fp8(w.z * 64.f); t8[d][vi + 3] = f2fp8(w.w * 64.f);
  }
  __syncthreads();
  // transposed fp8 write: wave-coalesced 16B chunks
  int vr = tid >> 2, dc = (tid & 3) << 4;
  union { u8 b[16]; ulonglong2 q; } u;
#pragma unroll
  for (int k = 0; k < 16; ++k) u.b[k] = t8[dc + k][vr];
  *(ulonglong2*)(WT8 + (size_t)(v0 + vr) * DDIM + d0 + dc) = u.q;
  // exact chosen dots from the pre-bucketed list: one wave per match
  int m0 = boff[blockIdx.x], m1 = boff[blockIdx.x + 1];
  int lane = tid & 63, wv = tid >> 6;
  for (int m = m0 + wv; m < m1; m += 4) {
    int e = bent[m];
    int r = e >> 6, cv = e & 63;
    int b = r / 1023, tt = r % 1023;
    float s = hs[(size_t)((b << 10) + tt) * DDIM + d0 + lane] * t32[lane][cv];
#pragma unroll
    for (int o = 1; o < 64; o <<= 1) s += __shfl_xor(s, o, 64);
    if (lane == 0) atomicAdd(chlog + r, s);
  }
}

// ---------- kernel 4: 128x256 fp8 GEMM (mfma_scale 16x16x128) + online-LSE -
// A8: [4096][2048] fp8 (x16, zero-padded rows), Bt8: [32768][2048] fp8 (x64)
// 8 waves (2x4), wave tile 64x64 -> acc[4][4] = 64 AGPRs (no spill, R10 ✓).
// LDS 96 KiB: [buf(49152)][A 16K | B 32K], rows of 128 B.
// SLOT REMAP vs R10: fragment half u now at slot ((u<<2)|g4)^xr — the bit
// placement measured 0-conflict in R3/R5/R6 — instead of ((g4<<1)|u)^xr
// (2.5-3.4e7 conflicts, R7-R10). Both operands see the same k-permutation
// (chunks {g4,4+g4} per lane), which cancels in the MFMA k-sum.
__global__ __launch_bounds__(512, 2) void gemm_lse(
    const u8* __restrict__ A, const u8* __restrict__ Bt,
    float2* __restrict__ partials) {
  extern __shared__ u16 smem[];
  char* lds = (char*)smem;

  const int tid = threadIdx.x;
  const int l = tid & 63;
  const int wid = tid >> 6;                // 8 waves
  const int wmr = wid >> 2, wnr = wid & 3; // 2 x 4
  const int ln = l & 15;
  const int g4 = l >> 4;
  const int xr = ln & 7;

  // XCD-bijective swizzle (4096 % 8 == 0): each XCD owns 16 bn panels
  int bid = blockIdx.x;
  int id = ((bid & 7) << 9) | (bid >> 3);
  int bm = id & 31;                  // 0..31 (M tiles of 128)
  int bn = id >> 5;                  // 0..127 (N tiles of 256)
  const int m0 = bm << 7, n0 = bn << 8;

  const u8* Ab = A + (size_t)m0 * DDIM;
  const u8* Bb = Bt + (size_t)n0 * DDIM;

  // swizzled LDS read offsets: half u at slot ((u<<2)|g4) ^ xr, 16B units
  const unsigned aA0 = (unsigned)(((wmr << 6) | ln) << 7) + ((((0 << 2) | g4) ^ xr) << 4);
  const unsigned aA1 = (unsigned)(((wmr << 6) | ln) << 7) + ((((1 << 2) | g4) ^ xr) << 4);
  const unsigned aB0 = 16384u + (unsigned)(((wnr << 6) | ln) << 7) + ((((0 << 2) | g4) ^ xr) << 4);
  const unsigned aB1 = 16384u + (unsigned)(((wnr << 6) | ln) << 7) + ((((1 << 2) | g4) ^ xr) << 4);

  // staging: lane voffsets (pre-permuted source), wave-uniform dest pieces
  const int srow = l >> 3;
  const unsigned selb = (unsigned)(((l & 7) ^ srow) << 4);   // bytes
  const unsigned voff0 = (unsigned)((((0  + wid) << 3) | srow) * 2048) + selb; // rows 0..63
  const unsigned voff1 = (unsigned)((((8  + wid) << 3) | srow) * 2048) + selb; // rows 64..127
  const unsigned voff2 = (unsigned)((((16 + wid) << 3) | srow) * 2048) + selb; // rows 128..191
  const unsigned voff3 = (unsigned)((((24 + wid) << 3) | srow) * 2048) + selb; // rows 192..255
  const int w10 = wid << 10;

#define RFL(x) __builtin_amdgcn_readfirstlane((int)(x))
#define GLL(src, dst) gload16((src), lds + RFL(dst))
#define LD4(off) (*(const i32x4*)(lds + (off)))
#define FRAG(b0, b1, o) SHUF(LD4((b0) + (o)), LD4((b1) + (o)))

#define MFMA4(q, af) do {                                                      \
    __builtin_amdgcn_s_setprio(1);                                             \
    _Pragma("unroll")                                                          \
    for (int _ni = 0; _ni < 4; ++_ni)                                          \
      acc[(q)][_ni] = __builtin_amdgcn_mfma_scale_f32_16x16x128_f8f6f4(        \
          (af), bf[_ni], acc[(q)][_ni], 0, 0, 0, SC8, 0, SC8);                 \
    __builtin_amdgcn_s_setprio(0);                                             \
  } while (0)

  f32x4 acc[4][4] = {};

  // prologue: A(0),B(0) -> buf0; B(1) -> buf1; wait tile0, leave B(1) in flight
  GLL(Ab + voff0, w10);                 GLL(Ab + voff1, 8192 + w10);
  GLL(Bb + voff0, 16384 + w10);         GLL(Bb + voff1, 24576 + w10);
  GLL(Bb + voff2, 32768 + w10);         GLL(Bb + voff3, 40960 + w10);
  GLL(Bb + 128 + voff0, BUFB + 16384 + w10);
  GLL(Bb + 128 + voff1, BUFB + 24576 + w10);
  GLL(Bb + 128 + voff2, BUFB + 32768 + w10);
  GLL(Bb + 128 + voff3, BUFB + 40960 + w10);
  asm volatile("s_waitcnt vmcnt(4)" ::: "memory"); SB();
  BAR();
  SB();

  for (int t = 0; t < 16; ++t) {
    const unsigned fb = (unsigned)(t & 1) * BUFB;    // current buf byte offset
    const unsigned fbn = BUFB - fb;                  // next buf
    const u8* baseA = Ab + ((t + 1) << 7);           // A(t+1), uniform
    const u8* baseB = Bb + ((t + 2) << 7);           // B(t+2), uniform
    const unsigned rA0 = fb + aA0, rA1 = fb + aA1;
    const unsigned rB0 = fb + aB0, rB1 = fb + aB1;

    // B operands for the whole tile (8 ds_read_b128 -> 4 x i32x8)
    i32x8 bf[4];
#pragma unroll
    for (int ni = 0; ni < 4; ++ni) bf[ni] = FRAG(rB0, rB1, ni * 2048);

    // ---- q0: A rows 0..15; stage A(t+1) half0
    i32x8 af = FRAG(rA0, rA1, 0);
    if (t < 15) GLL(baseA + voff0, fbn + w10);
    MFMA4(0, af);
    // ---- q1: A rows 16..31; stage A(t+1) half1
    af = FRAG(rA0, rA1, 2048);
    if (t < 15) GLL(baseA + voff1, fbn + 8192 + w10);
    MFMA4(1, af);
    SB();
    BAR();   // mid-tile: all waves' bf consumed -> B-space(fb) writable
    SB();
    // ---- q2: A rows 32..47; stage B(t+2) rows 0..127
    af = FRAG(rA0, rA1, 4096);
    if (t < 14) { GLL(baseB + voff0, fb + 16384 + w10);
                  GLL(baseB + voff1, fb + 24576 + w10); }
    MFMA4(2, af);
    // ---- q3: A rows 48..63; stage B(t+2) rows 128..255; counted vmcnt; flip
    af = FRAG(rA0, rA1, 6144);
    if (t < 14) { GLL(baseB + voff2, fb + 32768 + w10);
                  GLL(baseB + voff3, fb + 40960 + w10); }
    MFMA4(3, af);
    if (t < 14)       { asm volatile("s_waitcnt vmcnt(4)" ::: "memory"); }
    else if (t == 14) { asm volatile("s_waitcnt vmcnt(0)" ::: "memory"); }
    SB();
    BAR();   // boundary: tile t+1 fully landed, flip buffer
    SB();
  }

  // epilogue: per-row (max, sum-exp) over this wave's 64 cols (scale /1024)
  // C/D layout: col = lane&15, row = (lane>>4)*4 + reg
  const int chunk = (bn << 2) | wnr;
#pragma unroll
  for (int mi = 0; mi < 4; ++mi) {
#pragma unroll
    for (int rr = 0; rr < 4; ++rr) {
      const int row = m0 + (wmr << 6) + (mi << 4) + (g4 << 2) + rr;
      float v0 = acc[mi][0][rr] * 0.0009765625f;
      float v1 = acc[mi][1][rr] * 0.0009765625f;
      float v2 = acc[mi][2][rr] * 0.0009765625f;
      float v3 = acc[mi][3][rr] * 0.0009765625f;
      float mx = fmaxf(fmaxf(v0, v1), fmaxf(v2, v3));
#pragma unroll
      for (int o = 1; o < 16; o <<= 1) mx = fmaxf(mx, __shfl_xor(mx, o, 64));
      float s = __expf(v0 - mx) + __expf(v1 - mx) + __expf(v2 - mx) + __expf(v3 - mx);
#pragma unroll
      for (int o = 1; o < 16; o <<= 1) s += __shfl_xor(s, o, 64);
      if (ln == 0) partials[(size_t)row * NCHUNK + chunk] = make_float2(mx, s);
    }
  }
#undef MFMA4
#undef FRAG
#undef LD4
#undef GLL
#undef RFL
}

// ---------- kernel 5: combine partials -> lse -> logps -> loss terms ----------
__global__ void reduce_lse(const float2* __restrict__ partials,
                           const float* __restrict__ chlog,
                           const float* __restrict__ oldlp,
                           const int* __restrict__ labels,
                           const float* __restrict__ adv,
                           float* __restrict__ out, float* __restrict__ accum) {
  const int wid = threadIdx.x >> 6, l = threadIdx.x & 63;
  const int row = blockIdx.x * 4 + wid;        // 1023*4 = 4092 exactly
  float M = -INFINITY, S = 0.f;
  for (int c = l; c < NCHUNK; c += 64) {
    float2 p = partials[(size_t)row * NCHUNK + c];
    float Mn = fmaxf(M, p.x);
    S = S * __expf(M - Mn) + p.y * __expf(p.x - Mn);
    M = Mn;
  }
#pragma unroll
  for (int o = 1; o < 64; o <<= 1) {
    float Mo = __shfl_xor(M, o, 64), So = __shfl_xor(S, o, 64);
    float Mn = fmaxf(M, Mo);
    S = S * __expf(M - Mn) + So * __expf(Mo - Mn);
    M = Mn;
  }
  if (l == 0) {
    float lse = M + __logf(S);
    float ptl = chlog[row] - lse;
    out[1 + row] = ptl;
    int b = row / 1023, t = row % 1023;
    float a = adv[b];
    float ratio = __expf(ptl - oldlp[row]);
    float l1 = ratio * a;
    float l2 = fminf(fmaxf(ratio, 0.8f), 1.3f) * a;
    float mk = (float)labels[b * 1024 + t + 1];
    atomicAdd(accum + 0, -fminf(l1, l2) * mk);
    atomicAdd(accum + 1, mk);
  }
}

__global__ void finalize_k(const float* __restrict__ accum, float* __restrict__ out) {
  out[0] = accum[0] / accum[1];
}

// ---------- launch ----------
extern "C" void kernel_launch(void* const* d_in, const int* in_sizes, int n_in,
                              void* d_out, int out_size, void* d_ws, size_t ws_size,
                              hipStream_t stream) {
  const float* hs     = (const float*)d_in[0];   // (4,1024,2048)
  const float* W      = (const float*)d_in[1];   // (2048,32768)
  const int*   ids    = (const int*)d_in[2];     // (4,1024)
  const int*   labels = (const int*)d_in[3];     // (4,1024)
  const float* adv    = (const float*)d_in[4];   // (4,)
  const float* oldlp  = (const float*)d_in[5];   // (4,1023)
  float* out = (float*)d_out;                    // [loss, 4092 x per_token_logps]

  // ws layout (~92.4 MB)
  char* ws = (char*)d_ws;
  u8*     WT8      = (u8*)ws;                          //  67,108,864 B
  u8*     h8       = (u8*)(ws + 67108864);             //   8,388,608 B
  float2* partials = (float2*)(ws + 75497472);         //  16,777,216 B
  float*  chlog    = (float*)(ws + 92274688);          //      16,384 B
  int*    chosen   = (int*)(ws + 92291072);            //      16,384 B
  float*  accum    = (float*)(ws + 92307456);          //          64 B (pad)
  int*    boff     = (int*)(ws + 92307520);            //       2,112 B (513+pad)
  int*    bent     = (int*)(ws + 92309632);            //      16,384 B

  (void)hipFuncSetAttribute((const void*)gemm_lse,
                            hipFuncAttributeMaxDynamicSharedMemorySize, 98304);

  init_k<<<16, 256, 0, stream>>>(ids, chosen, chlog, accum);
  bucket_k<<<1, 512, 0, stream>>>(chosen, boff, bent);
  conv_h<<<4096, 256, 0, stream>>>(hs, h8);
  transpose_w<<<dim3(512, 32), 256, 0, stream>>>(W, WT8, hs, boff, bent, chlog);
  gemm_lse<<<4096, 512, 98304, stream>>>(h8, WT8, partials);
  reduce_lse<<<1023, 256, 0, stream>>>(partials, chlog, oldlp, labels, adv, out, accum);
  finalize_k<<<1, 1, 0, stream>>>(accum, out);
}